// Round 8
// baseline (368.062 us; speedup 1.0000x reference)
//
#include <hip/hip_runtime.h>
#include <math.h>

typedef unsigned int u32;
typedef unsigned short u16;
typedef __attribute__((ext_vector_type(8))) short bf16x8;
typedef __attribute__((ext_vector_type(4))) float f32x4;
typedef __attribute__((ext_vector_type(2))) float f32x2;

static constexpr int TNFEAT  = 128;
static constexpr int TNHEADS = 8;
static constexpr int C1      = 512;  // NHID*NHEADS
static constexpr int C2      = 64;   // NCLASS

__device__ inline float bf2f(u16 u) {
  union { u32 i; float f; } c; c.i = ((u32)u) << 16; return c.f;
}
__device__ inline float bitsf(u32 u) {
  union { u32 i; float f; } c; c.i = u; return c.f;
}
__device__ inline u16 f2bf(float f) {
  union { float f; u32 i; } c; c.f = f;
  u32 r = c.i + 0x7FFF + ((c.i >> 16) & 1);   // round-nearest-even
  return (u16)(r >> 16);
}
__device__ inline u32 cvt_pk_bf16(float lo, float hi) {
  u32 r;
  asm volatile("v_cvt_pk_bf16_f32 %0, %1, %2" : "=v"(r) : "v"(lo), "v"(hi));
  return r;
}
__device__ inline uint4 ld16(const u16* base, u32 byteoff) {
  return *reinterpret_cast<const uint4*>(reinterpret_cast<const char*>(base) + byteoff);
}
__device__ inline f32x2 up2(u32 q) {
  f32x2 p;
  p.x = bitsf(q << 16);
  p.y = bitsf(q & 0xffff0000u);
  return p;
}

__global__ void k_zero(int* __restrict__ p, int n) {
  int i = blockIdx.x * blockDim.x + threadIdx.x;
  if (i < n) p[i] = 0;
}

__global__ void k_hist(const int* __restrict__ src, int* __restrict__ deg, int E) {
  int i = blockIdx.x * blockDim.x + threadIdx.x;
  if (i < E) atomicAdd(&deg[src[i]], 1);
}

__global__ __launch_bounds__(1024) void k_bscan1(const int* __restrict__ deg,
                                                 int* __restrict__ loc,
                                                 int* __restrict__ bsum, int n) {
  __shared__ int sdata[1024];
  int t = threadIdx.x;
  int i = blockIdx.x * 1024 + t;
  int v = (i < n) ? deg[i] : 0;
  sdata[t] = v;
  __syncthreads();
  for (int ofs = 1; ofs < 1024; ofs <<= 1) {
    int tv = (t >= ofs) ? sdata[t - ofs] : 0;
    __syncthreads();
    sdata[t] += tv;
    __syncthreads();
  }
  if (i < n) loc[i] = sdata[t];
  if (t == 1023) bsum[blockIdx.x] = sdata[1023];
}

__global__ void k_bscan2(int* __restrict__ bsum, int nb) {
  int t = threadIdx.x;
  int v = (t < nb) ? bsum[t] : 0;
  #pragma unroll
  for (int ofs = 1; ofs < 64; ofs <<= 1) {
    int u = __shfl_up(v, ofs);
    if (t >= ofs) v += u;
  }
  if (t < nb) bsum[t] = v;
}

__global__ __launch_bounds__(1024) void k_offs(const int* __restrict__ loc,
                                               const int* __restrict__ bsum,
                                               const int* __restrict__ deg,
                                               int* __restrict__ offs,
                                               int* __restrict__ cur, int n) {
  int b = blockIdx.x;
  int i = b * 1024 + threadIdx.x;
  int base = (b > 0) ? bsum[b - 1] : 0;
  if (i < n) {
    int v = base + loc[i];
    offs[i + 1] = v;
    cur[i] = v - deg[i];
  }
  if (i == 0) offs[0] = 0;
}

__global__ void k_fill(const int* __restrict__ src, const int* __restrict__ dst,
                       int* __restrict__ cur, int* __restrict__ adj, int E) {
  int i = blockIdx.x * blockDim.x + threadIdx.x;
  if (i < E) {
    int p = atomicAdd(&cur[src[i]], 1);
    adj[p] = dst[i];
  }
}

// Pack W1 [8][128][64] into MFMA b-frag order (cg = head*4+cf)
__global__ void k_packW1(const float* __restrict__ W1, u16* __restrict__ hi,
                         u16* __restrict__ lo) {
  int idx = blockIdx.x * 256 + threadIdx.x;
  if (idx >= 32 * 4 * 64 * 8) return;
  int j = idx & 7, lane = (idx >> 3) & 63, ks = (idx >> 9) & 3, cg = idx >> 11;
  int col = cg * 16 + (lane & 15);
  int k = ks * 32 + (lane >> 4) * 8 + j;
  float f = W1[((size_t)(col >> 6) * 128 + k) * 64 + (col & 63)];
  u16 h = f2bf(f);
  hi[idx] = h;
  lo[idx] = f2bf(f - bf2f(h));
}

// Pack W2 [8][512][8]
__global__ void k_packW2(const float* __restrict__ W2, u16* __restrict__ hi,
                         u16* __restrict__ lo) {
  int idx = blockIdx.x * 256 + threadIdx.x;
  if (idx >= 4 * 16 * 64 * 8) return;
  int j = idx & 7, lane = (idx >> 3) & 63, ks = (idx >> 9) & 15, cg = idx >> 13;
  int col = cg * 16 + (lane & 15);
  int k = ks * 32 + (lane >> 4) * 8 + j;
  float f = W2[((size_t)(col >> 3) * 512 + k) * 8 + (col & 7)];
  u16 h = f2bf(f);
  hi[idx] = h;
  lo[idx] = f2bf(f - bf2f(h));
}

// Vsd[k][c] = sum_f W1[h][k][f] * a1[h][s*64+f], c = h*2+s; packed in b-frag order.
__global__ void k_packVsd(const float* __restrict__ W1, const float* __restrict__ a1,
                          u16* __restrict__ vhi, u16* __restrict__ vlo) {
  int idx = blockIdx.x * 256 + threadIdx.x;   // 2048 total
  if (idx >= 2048) return;
  int j = idx & 7, lane = (idx >> 3) & 63, ks = idx >> 9;
  int k = ks * 32 + (lane >> 4) * 8 + j;
  int c = lane & 15;
  int h = c >> 1, s = c & 1;
  const float* wrow = W1 + ((size_t)h * 128 + k) * 64;
  const float* av = a1 + h * 128 + s * 64;
  float dot = 0.f;
  #pragma unroll 8
  for (int f = 0; f < 64; f++) dot = fmaf(wrow[f], av[f], dot);
  u16 hb = f2bf(dot);
  vhi[idx] = hb;
  vlo[idx] = f2bf(dot - bf2f(hb));
}

// x [N,128] fp32 -> xb bf16 [N,128]; scores [N,16] = x @ Vsd -> s1s/s1d (3-term MFMA)
__global__ __launch_bounds__(256) void k_xprep(const float* __restrict__ x,
        const u16* __restrict__ vhi, const u16* __restrict__ vlo,
        u16* __restrict__ xb, float* __restrict__ ss, float* __restrict__ sd, int N) {
  int w = threadIdx.x >> 6, lane = threadIdx.x & 63;
  int lr = lane & 15, lk = lane >> 4;
  int row0 = blockIdx.x * 64 + w * 16;
  f32x4 acc = {0.f, 0.f, 0.f, 0.f};
  for (int ks = 0; ks < 4; ++ks) {
    int row = row0 + lr;
    int rc = row < N ? row : 0;
    const float* ap = x + (size_t)rc * 128 + ks * 32 + lk * 8;
    float4 f0 = *reinterpret_cast<const float4*>(ap);
    float4 f1 = *reinterpret_cast<const float4*>(ap + 4);
    float fa[8] = {f0.x, f0.y, f0.z, f0.w, f1.x, f1.y, f1.z, f1.w};
    union { u32 u[4]; bf16x8 v; uint4 q; } ch, cl;
    #pragma unroll
    for (int p = 0; p < 4; ++p) {
      float e0 = fa[2 * p], e1 = fa[2 * p + 1];
      u32 h = cvt_pk_bf16(e0, e1);
      ch.u[p] = h;
      cl.u[p] = cvt_pk_bf16(e0 - bitsf(h << 16), e1 - bitsf(h & 0xffff0000u));
    }
    if (row < N)
      *reinterpret_cast<uint4*>(&xb[(size_t)row * 128 + ks * 32 + lk * 8]) = ch.q;
    size_t bidx = ((size_t)ks * 64 + lane) * 8;
    bf16x8 Bh = *reinterpret_cast<const bf16x8*>(&vhi[bidx]);
    bf16x8 Bl = *reinterpret_cast<const bf16x8*>(&vlo[bidx]);
    acc = __builtin_amdgcn_mfma_f32_16x16x32_bf16(ch.v, Bh, acc, 0, 0, 0);
    acc = __builtin_amdgcn_mfma_f32_16x16x32_bf16(cl.v, Bh, acc, 0, 0, 0);
    acc = __builtin_amdgcn_mfma_f32_16x16x32_bf16(ch.v, Bl, acc, 0, 0, 0);
  }
  int h = lr >> 1, s = lr & 1;
  float* dstp = (s == 0) ? ss : sd;
  #pragma unroll
  for (int r = 0; r < 4; ++r) {
    int row = row0 + lk * 4 + r;
    if (row < N) dstp[row * 8 + h] = acc[r];
  }
}

// Fused layer-1: x-space aggregation into LDS + per-head MFMA GEMM + rsum/elu.
// Block = 16 nodes (4 waves x 4 nodes sequential). LDS g: 16 x 2064 B (padded).
__global__ __launch_bounds__(256) void k_l1f(const u16* __restrict__ xb,
        const float* __restrict__ ss, const float* __restrict__ sd,
        const int* __restrict__ offs, const int* __restrict__ adj,
        const u16* __restrict__ bhi, const u16* __restrict__ blo,
        u16* __restrict__ h1p, int N) {
  __shared__ u32 g_lds[16 * 516];      // 516 u32 = 2064 B per node slot
  __shared__ float rs_lds[16][8];
  int w = threadIdx.x >> 6, lane = threadIdx.x & 63;
  int head = lane >> 3, li = lane & 7;
  int nodebase = blockIdx.x * 16;

  // ---- Phase 1: aggregation, 4 nodes per wave ----
  for (int q = 0; q < 4; ++q) {
    int slot = w * 4 + q;
    int node = nodebase + slot;
    f32x2 acc2[8] = {};
    float rsum = 0.f;
    if (node < N) {
      int beg = offs[node], end = offs[node + 1];
      float sS = ss[node * 8 + head];
      int e = beg;
      for (; e + 8 <= end; e += 8) {
        int dl = adj[e + li];
        float z = sS + sd[(u32)dl * 8u + head];
        float wgt = __expf(-(z > 0.f ? z : 0.2f * z));
        rsum += wgt;
        int dr[8];
        #pragma unroll
        for (int i = 0; i < 8; i++) dr[i] = __shfl(dl, i);
        u32 qv[8];
        #pragma unroll
        for (int i = 0; i < 8; i++)
          qv[i] = *reinterpret_cast<const u32*>(
              reinterpret_cast<const char*>(xb) + (u32)dr[i] * 256u + lane * 4u);
        #pragma unroll
        for (int i = 0; i < 8; i++) {
          f32x2 xv = up2(qv[i]);
          #pragma unroll
          for (int h2 = 0; h2 < 8; h2++) {
            float wi = __shfl(wgt, h2 * 8 + i);
            acc2[h2] += (f32x2){wi, wi} * xv;
          }
        }
      }
      if (e < end) {
        int m = end - e;
        int lic = li < m ? li : m - 1;
        int dl = adj[e + lic];
        float z = sS + sd[(u32)dl * 8u + head];
        float wgt = __expf(-(z > 0.f ? z : 0.2f * z));
        if (li >= m) wgt = 0.f;
        rsum += wgt;
        int dr[8];
        #pragma unroll
        for (int i = 0; i < 8; i++) dr[i] = __shfl(dl, i);
        u32 qv[8];
        #pragma unroll
        for (int i = 0; i < 8; i++)
          if (i < m)
            qv[i] = *reinterpret_cast<const u32*>(
                reinterpret_cast<const char*>(xb) + (u32)dr[i] * 256u + lane * 4u);
        #pragma unroll
        for (int i = 0; i < 8; i++) {
          if (i < m) {
            f32x2 xv = up2(qv[i]);
            #pragma unroll
            for (int h2 = 0; h2 < 8; h2++) {
              float wi = __shfl(wgt, h2 * 8 + i);
              acc2[h2] += (f32x2){wi, wi} * xv;
            }
          }
        }
      }
      rsum += __shfl_xor(rsum, 1);
      rsum += __shfl_xor(rsum, 2);
      rsum += __shfl_xor(rsum, 4);
    }
    u32* gu = g_lds + slot * 516;
    #pragma unroll
    for (int h2 = 0; h2 < 8; h2++)
      gu[h2 * 64 + lane] = cvt_pk_bf16(acc2[h2].x, acc2[h2].y);
    if (li == 0) rs_lds[slot][head] = rsum;
  }
  __syncthreads();

  // ---- Phase 2: per-head GEMM on LDS g; wave w -> heads 2w, 2w+1 ----
  int lr = lane & 15, lk = lane >> 4;
  int h0 = 2 * w, h1h = 2 * w + 1;
  f32x4 acc[2][4] = {};
  const char* gb = reinterpret_cast<const char*>(g_lds);
  for (int ks = 0; ks < 4; ++ks) {
    bf16x8 A0 = *reinterpret_cast<const bf16x8*>(
        gb + lr * 2064 + h0 * 256 + ks * 64 + lk * 16);
    bf16x8 A1 = *reinterpret_cast<const bf16x8*>(
        gb + lr * 2064 + h1h * 256 + ks * 64 + lk * 16);
    #pragma unroll
    for (int cf = 0; cf < 4; ++cf) {
      size_t b0 = ((size_t)((h0 * 4 + cf) * 4 + ks) * 64 + lane) * 8;
      bf16x8 Bh = *reinterpret_cast<const bf16x8*>(&bhi[b0]);
      bf16x8 Bl = *reinterpret_cast<const bf16x8*>(&blo[b0]);
      acc[0][cf] = __builtin_amdgcn_mfma_f32_16x16x32_bf16(A0, Bh, acc[0][cf], 0, 0, 0);
      acc[0][cf] = __builtin_amdgcn_mfma_f32_16x16x32_bf16(A0, Bl, acc[0][cf], 0, 0, 0);
      size_t b1 = ((size_t)((h1h * 4 + cf) * 4 + ks) * 64 + lane) * 8;
      bf16x8 Ch = *reinterpret_cast<const bf16x8*>(&bhi[b1]);
      bf16x8 Cl = *reinterpret_cast<const bf16x8*>(&blo[b1]);
      acc[1][cf] = __builtin_amdgcn_mfma_f32_16x16x32_bf16(A1, Ch, acc[1][cf], 0, 0, 0);
      acc[1][cf] = __builtin_amdgcn_mfma_f32_16x16x32_bf16(A1, Cl, acc[1][cf], 0, 0, 0);
    }
  }
  #pragma unroll
  for (int r = 0; r < 4; ++r) {
    int slot = lk * 4 + r;
    int node = nodebase + slot;
    if (node < N) {
      float inv0 = 1.f / rs_lds[slot][h0];
      float inv1 = 1.f / rs_lds[slot][h1h];
      #pragma unroll
      for (int cf = 0; cf < 4; ++cf) {
        float v0 = acc[0][cf][r] * inv0;
        v0 = v0 > 0.f ? v0 : expm1f(v0);
        h1p[(size_t)node * 512 + h0 * 64 + cf * 16 + lr] = (u16)cvt_pk_bf16(v0, v0);
        float v1 = acc[1][cf][r] * inv1;
        v1 = v1 > 0.f ? v1 : expm1f(v1);
        h1p[(size_t)node * 512 + h1h * 64 + cf * 16 + lr] = (u16)cvt_pk_bf16(v1, v1);
      }
    }
  }
}

// GEMM2: bf16 [N,512] x [512,64] -> bf16 [N,64] + fused scores.
__global__ __launch_bounds__(256) void k_mgemm2(const u16* __restrict__ A,
        const u16* __restrict__ bhi, const u16* __restrict__ blo,
        const float* __restrict__ a2, u16* __restrict__ H2,
        float* __restrict__ ss, float* __restrict__ sdst, int N) {
  int w = threadIdx.x >> 6, lane = threadIdx.x & 63;
  int lr = lane & 15, lk = lane >> 4;
  int row0 = blockIdx.x * 128 + w * 32;
  f32x4 acc[2][4] = {};
  for (int ks = 0; ks < 16; ++ks) {
    bf16x8 Ah[2];
    #pragma unroll
    for (int rf = 0; rf < 2; ++rf) {
      int row = row0 + rf * 16 + lr;
      int rc = row < N ? row : 0;
      size_t aidx = (size_t)rc * 512 + ks * 32 + lk * 8;
      Ah[rf] = *reinterpret_cast<const bf16x8*>(&A[aidx]);
    }
    #pragma unroll
    for (int cf = 0; cf < 4; ++cf) {
      size_t bidx = ((size_t)(cf * 16 + ks) * 64 + lane) * 8;
      bf16x8 Bh = *reinterpret_cast<const bf16x8*>(&bhi[bidx]);
      bf16x8 Bl = *reinterpret_cast<const bf16x8*>(&blo[bidx]);
      #pragma unroll
      for (int rf = 0; rf < 2; ++rf) {
        acc[rf][cf] = __builtin_amdgcn_mfma_f32_16x16x32_bf16(Ah[rf], Bh, acc[rf][cf], 0, 0, 0);
        acc[rf][cf] = __builtin_amdgcn_mfma_f32_16x16x32_bf16(Ah[rf], Bl, acc[rf][cf], 0, 0, 0);
      }
    }
  }
  int hh = lr >> 3, jj = lr & 7;
  float a2s[4], a2d[4];
  #pragma unroll
  for (int cf = 0; cf < 4; ++cf) {
    int h = cf * 2 + hh;
    a2s[cf] = a2[h * 16 + jj];
    a2d[cf] = a2[h * 16 + 8 + jj];
  }
  #pragma unroll
  for (int rf = 0; rf < 2; ++rf) {
    #pragma unroll
    for (int r = 0; r < 4; ++r) {
      int row = row0 + rf * 16 + lk * 4 + r;
      if (row < N) {
        #pragma unroll
        for (int cf = 0; cf < 4; ++cf)
          H2[(size_t)row * 64 + cf * 16 + lr] =
              (u16)cvt_pk_bf16(acc[rf][cf][r], acc[rf][cf][r]);
      }
      float ps[4], pd[4];
      #pragma unroll
      for (int cf = 0; cf < 4; ++cf) {
        ps[cf] = acc[rf][cf][r] * a2s[cf];
        pd[cf] = acc[rf][cf][r] * a2d[cf];
      }
      #pragma unroll
      for (int m = 1; m < 8; m <<= 1) {
        #pragma unroll
        for (int cf = 0; cf < 4; ++cf) {
          ps[cf] += __shfl_xor(ps[cf], m);
          pd[cf] += __shfl_xor(pd[cf], m);
        }
      }
      if (jj == 0 && row < N) {
        #pragma unroll
        for (int cf = 0; cf < 4; ++cf) {
          int h = cf * 2 + hh;
          ss[row * 8 + h]   = ps[cf];
          sdst[row * 8 + h] = pd[cf];
        }
      }
    }
  }
}

// Layer-2 aggregation: one wave per node; lane = (li = lane>>3, fg = lane&7).
__global__ __launch_bounds__(256) void k_agg2(const u16* __restrict__ H,
        const float* __restrict__ ss, const float* __restrict__ sd,
        const int* __restrict__ offs, const int* __restrict__ adj,
        float* __restrict__ outp, int n) {
  int node = (blockIdx.x * 256 + threadIdx.x) >> 6;
  int lane = threadIdx.x & 63;
  if (node >= n) return;
  int li = lane >> 3, fg = lane & 7;
  int beg = offs[node], end = offs[node + 1];
  float sS = ss[node * 8 + fg];
  f32x2 acc2[4] = {};
  float rsum = 0.f;
  int e = beg;
  for (; e + 8 <= end; e += 8) {
    int dl = adj[e + (lane & 7)];
    u32 d = (u32)__shfl(dl, li);
    uint4 rv = ld16(H, d * 128u + fg * 16u);
    float z = sS + sd[d * 8u + fg];
    float w = __expf(-(z > 0.f ? z : 0.2f * z));
    rsum += w;
    f32x2 w2 = {w, w};
    acc2[0] += w2 * up2(rv.x);
    acc2[1] += w2 * up2(rv.y);
    acc2[2] += w2 * up2(rv.z);
    acc2[3] += w2 * up2(rv.w);
  }
  if (e < end) {
    int m = end - e;
    int ll = lane & 7; if (ll >= m) ll = m - 1;
    int dl = adj[e + ll];
    u32 d = (u32)__shfl(dl, li);
    if (li < m) {
      uint4 rv = ld16(H, d * 128u + fg * 16u);
      float z = sS + sd[d * 8u + fg];
      float w = __expf(-(z > 0.f ? z : 0.2f * z));
      rsum += w;
      f32x2 w2 = {w, w};
      acc2[0] += w2 * up2(rv.x);
      acc2[1] += w2 * up2(rv.y);
      acc2[2] += w2 * up2(rv.z);
      acc2[3] += w2 * up2(rv.w);
    }
  }
  #pragma unroll
  for (int mask = 8; mask < 64; mask <<= 1) {
    rsum += __shfl_xor(rsum, mask);
    #pragma unroll
    for (int k = 0; k < 4; k++) {
      acc2[k].x += __shfl_xor(acc2[k].x, mask);
      acc2[k].y += __shfl_xor(acc2[k].y, mask);
    }
  }
  if (li == 0) {
    float inv = 1.f / rsum;
    float o[8];
    #pragma unroll
    for (int k = 0; k < 4; k++) {
      float v0 = acc2[k].x * inv, v1 = acc2[k].y * inv;
      o[2 * k]     = v0 > 0.f ? v0 : expm1f(v0);
      o[2 * k + 1] = v1 > 0.f ? v1 : expm1f(v1);
    }
    float4* Ov = reinterpret_cast<float4*>(outp);
    Ov[(size_t)node * 16 + fg * 2]     = make_float4(o[0], o[1], o[2], o[3]);
    Ov[(size_t)node * 16 + fg * 2 + 1] = make_float4(o[4], o[5], o[6], o[7]);
  }
}

extern "C" void kernel_launch(void* const* d_in, const int* in_sizes, int n_in,
                              void* d_out, int out_size, void* d_ws, size_t ws_size,
                              hipStream_t stream) {
  const float* x  = (const float*)d_in[0];
  const int*   ei = (const int*)d_in[1];
  const float* W1 = (const float*)d_in[2];
  const float* a1 = (const float*)d_in[3];
  const float* W2 = (const float*)d_in[4];
  const float* a2 = (const float*)d_in[5];
  float* out = (float*)d_out;

  int N = in_sizes[0] / TNFEAT;   // 50000
  int E = in_sizes[1] / 2;        // 850000
  const int* src = ei;
  const int* dst = ei + E;
  int NB = (N + 1023) / 1024;

  char* base = (char*)d_ws;
  size_t off = 0;
  auto take = [&](size_t bytes) { char* p = base + off; off = (off + bytes + 255) & ~(size_t)255; return p; };
  u16*   xb    = (u16*)take((size_t)N * TNFEAT * 2);       // 12.8 MB
  u16*   h1    = (u16*)take((size_t)N * C1 * 2);           // 51.2 MB
  u16*   h2p   = (u16*)take((size_t)N * C2 * 2);           // 6.4 MB
  u16*   w1hi  = (u16*)take(65536 * 2);
  u16*   w1lo  = (u16*)take(65536 * 2);
  u16*   w2hi  = (u16*)take(32768 * 2);
  u16*   w2lo  = (u16*)take(32768 * 2);
  u16*   vhi   = (u16*)take(2048 * 2);
  u16*   vlo   = (u16*)take(2048 * 2);
  float* s1s   = (float*)take((size_t)N * 8 * 4);
  float* s1d   = (float*)take((size_t)N * 8 * 4);
  float* s2s   = (float*)take((size_t)N * 8 * 4);
  float* s2d   = (float*)take((size_t)N * 8 * 4);
  int*   deg   = (int*)take((size_t)N * 4);
  int*   offs  = (int*)take((size_t)(N + 1) * 4);
  int*   cur   = (int*)take((size_t)N * 4);
  int*   loc   = (int*)take((size_t)N * 4);
  int*   bsum  = (int*)take(64 * 4);
  int*   adj   = (int*)take((size_t)E * 4);

  // CSR build (by src)
  hipLaunchKernelGGL(k_zero, dim3((N + 255) / 256), dim3(256), 0, stream, deg, N);
  hipLaunchKernelGGL(k_hist, dim3((E + 255) / 256), dim3(256), 0, stream, src, deg, E);
  hipLaunchKernelGGL(k_bscan1, dim3(NB), dim3(1024), 0, stream, deg, loc, bsum, N);
  hipLaunchKernelGGL(k_bscan2, dim3(1), dim3(64), 0, stream, bsum, NB);
  hipLaunchKernelGGL(k_offs, dim3(NB), dim3(1024), 0, stream, loc, bsum, deg, offs, cur, N);
  hipLaunchKernelGGL(k_fill, dim3((E + 255) / 256), dim3(256), 0, stream, src, dst, cur, adj, E);

  // Weight packing + score-projection vectors
  hipLaunchKernelGGL(k_packW1, dim3(256), dim3(256), 0, stream, W1, w1hi, w1lo);
  hipLaunchKernelGGL(k_packW2, dim3(128), dim3(256), 0, stream, W2, w2hi, w2lo);
  hipLaunchKernelGGL(k_packVsd, dim3(8), dim3(256), 0, stream, W1, a1, vhi, vlo);

  // Layer 1: xb + scores, then fused aggregation + per-head GEMM
  hipLaunchKernelGGL(k_xprep, dim3((N + 63) / 64), dim3(256), 0, stream,
                     x, vhi, vlo, xb, s1s, s1d, N);
  hipLaunchKernelGGL(k_l1f, dim3((N + 15) / 16), dim3(256), 0, stream,
                     xb, s1s, s1d, offs, adj, w1hi, w1lo, h1, N);

  // Layer 2
  hipLaunchKernelGGL(k_mgemm2, dim3((N + 127) / 128), dim3(256), 0, stream,
                     h1, w2hi, w2lo, a2, h2p, s2s, s2d, N);
  hipLaunchKernelGGL(k_agg2, dim3((N + 3) / 4), dim3(256), 0, stream,
                     h2p, s2s, s2d, offs, adj, out, N);
}

// Round 9
// 328.509 us; speedup vs baseline: 1.1204x; 1.1204x over previous
//
#include <hip/hip_runtime.h>
#include <math.h>

typedef unsigned int u32;
typedef unsigned short u16;
typedef __attribute__((ext_vector_type(8))) short bf16x8;
typedef __attribute__((ext_vector_type(4))) float f32x4;
typedef __attribute__((ext_vector_type(2))) float f32x2;

static constexpr int TNFEAT  = 128;
static constexpr int TNHEADS = 8;
static constexpr int C1      = 512;  // NHID*NHEADS
static constexpr int C2      = 64;   // NCLASS

__device__ inline float bf2f(u16 u) {
  union { u32 i; float f; } c; c.i = ((u32)u) << 16; return c.f;
}
__device__ inline float bitsf(u32 u) {
  union { u32 i; float f; } c; c.i = u; return c.f;
}
__device__ inline u16 f2bf(float f) {
  union { float f; u32 i; } c; c.f = f;
  u32 r = c.i + 0x7FFF + ((c.i >> 16) & 1);   // round-nearest-even
  return (u16)(r >> 16);
}
__device__ inline u32 cvt_pk_bf16(float lo, float hi) {
  u32 r;
  asm volatile("v_cvt_pk_bf16_f32 %0, %1, %2" : "=v"(r) : "v"(lo), "v"(hi));
  return r;
}
__device__ inline uint4 ld16(const u16* base, u32 byteoff) {
  return *reinterpret_cast<const uint4*>(reinterpret_cast<const char*>(base) + byteoff);
}
__device__ inline f32x2 up2(u32 q) {
  f32x2 p;
  p.x = bitsf(q << 16);
  p.y = bitsf(q & 0xffff0000u);
  return p;
}

__global__ void k_zero(int* __restrict__ p, int n) {
  int i = blockIdx.x * blockDim.x + threadIdx.x;
  if (i < n) p[i] = 0;
}

__global__ void k_hist(const int* __restrict__ src, int* __restrict__ deg, int E) {
  int i = blockIdx.x * blockDim.x + threadIdx.x;
  if (i < E) atomicAdd(&deg[src[i]], 1);
}

__global__ __launch_bounds__(1024) void k_bscan1(const int* __restrict__ deg,
                                                 int* __restrict__ loc,
                                                 int* __restrict__ bsum, int n) {
  __shared__ int sdata[1024];
  int t = threadIdx.x;
  int i = blockIdx.x * 1024 + t;
  int v = (i < n) ? deg[i] : 0;
  sdata[t] = v;
  __syncthreads();
  for (int ofs = 1; ofs < 1024; ofs <<= 1) {
    int tv = (t >= ofs) ? sdata[t - ofs] : 0;
    __syncthreads();
    sdata[t] += tv;
    __syncthreads();
  }
  if (i < n) loc[i] = sdata[t];
  if (t == 1023) bsum[blockIdx.x] = sdata[1023];
}

__global__ void k_bscan2(int* __restrict__ bsum, int nb) {
  int t = threadIdx.x;
  int v = (t < nb) ? bsum[t] : 0;
  #pragma unroll
  for (int ofs = 1; ofs < 64; ofs <<= 1) {
    int u = __shfl_up(v, ofs);
    if (t >= ofs) v += u;
  }
  if (t < nb) bsum[t] = v;
}

__global__ __launch_bounds__(1024) void k_offs(const int* __restrict__ loc,
                                               const int* __restrict__ bsum,
                                               const int* __restrict__ deg,
                                               int* __restrict__ offs,
                                               int* __restrict__ cur, int n) {
  int b = blockIdx.x;
  int i = b * 1024 + threadIdx.x;
  int base = (b > 0) ? bsum[b - 1] : 0;
  if (i < n) {
    int v = base + loc[i];
    offs[i + 1] = v;
    cur[i] = v - deg[i];
  }
  if (i == 0) offs[0] = 0;
}

__global__ void k_fill(const int* __restrict__ src, const int* __restrict__ dst,
                       int* __restrict__ cur, int* __restrict__ adj, int E) {
  int i = blockIdx.x * blockDim.x + threadIdx.x;
  if (i < E) {
    int p = atomicAdd(&cur[src[i]], 1);
    adj[p] = dst[i];
  }
}

// One launch: blocks [0,256) pack W1, [256,384) pack W2, [384,392) pack Vsd.
__global__ void k_packAll(const float* __restrict__ W1, const float* __restrict__ W2,
                          const float* __restrict__ a1,
                          u16* __restrict__ w1hi, u16* __restrict__ w1lo,
                          u16* __restrict__ w2hi, u16* __restrict__ w2lo,
                          u16* __restrict__ vhi, u16* __restrict__ vlo) {
  int b = blockIdx.x;
  if (b < 256) {
    int idx = b * 256 + threadIdx.x;   // 65536
    int j = idx & 7, lane = (idx >> 3) & 63, ks = (idx >> 9) & 3, cg = idx >> 11;
    int col = cg * 16 + (lane & 15);
    int k = ks * 32 + (lane >> 4) * 8 + j;
    float f = W1[((size_t)(col >> 6) * 128 + k) * 64 + (col & 63)];
    u16 h = f2bf(f);
    w1hi[idx] = h;
    w1lo[idx] = f2bf(f - bf2f(h));
  } else if (b < 384) {
    int idx = (b - 256) * 256 + threadIdx.x;   // 32768
    int j = idx & 7, lane = (idx >> 3) & 63, ks = (idx >> 9) & 15, cg = idx >> 13;
    int col = cg * 16 + (lane & 15);
    int k = ks * 32 + (lane >> 4) * 8 + j;
    float f = W2[((size_t)(col >> 3) * 512 + k) * 8 + (col & 7)];
    u16 h = f2bf(f);
    w2hi[idx] = h;
    w2lo[idx] = f2bf(f - bf2f(h));
  } else {
    int idx = (b - 384) * 256 + threadIdx.x;   // 2048
    int j = idx & 7, lane = (idx >> 3) & 63, ks = idx >> 9;
    int k = ks * 32 + (lane >> 4) * 8 + j;
    int c = lane & 15;
    int h = c >> 1, s = c & 1;
    const float* wrow = W1 + ((size_t)h * 128 + k) * 64;
    const float* av = a1 + h * 128 + s * 64;
    float dot = 0.f;
    #pragma unroll 8
    for (int f = 0; f < 64; f++) dot = fmaf(wrow[f], av[f], dot);
    u16 hb = f2bf(dot);
    vhi[idx] = hb;
    vlo[idx] = f2bf(dot - bf2f(hb));
  }
}

// x [N,128] fp32 -> xb bf16 [N,128]; scores [N,16] = x @ Vsd -> s1s/s1d (3-term MFMA)
__global__ __launch_bounds__(256) void k_xprep(const float* __restrict__ x,
        const u16* __restrict__ vhi, const u16* __restrict__ vlo,
        u16* __restrict__ xb, float* __restrict__ ss, float* __restrict__ sd, int N) {
  int w = threadIdx.x >> 6, lane = threadIdx.x & 63;
  int lr = lane & 15, lk = lane >> 4;
  int row0 = blockIdx.x * 64 + w * 16;
  f32x4 acc = {0.f, 0.f, 0.f, 0.f};
  for (int ks = 0; ks < 4; ++ks) {
    int row = row0 + lr;
    int rc = row < N ? row : 0;
    const float* ap = x + (size_t)rc * 128 + ks * 32 + lk * 8;
    float4 f0 = *reinterpret_cast<const float4*>(ap);
    float4 f1 = *reinterpret_cast<const float4*>(ap + 4);
    float fa[8] = {f0.x, f0.y, f0.z, f0.w, f1.x, f1.y, f1.z, f1.w};
    union { u32 u[4]; bf16x8 v; uint4 q; } ch, cl;
    #pragma unroll
    for (int p = 0; p < 4; ++p) {
      float e0 = fa[2 * p], e1 = fa[2 * p + 1];
      u32 h = cvt_pk_bf16(e0, e1);
      ch.u[p] = h;
      cl.u[p] = cvt_pk_bf16(e0 - bitsf(h << 16), e1 - bitsf(h & 0xffff0000u));
    }
    if (row < N)
      *reinterpret_cast<uint4*>(&xb[(size_t)row * 128 + ks * 32 + lk * 8]) = ch.q;
    size_t bidx = ((size_t)ks * 64 + lane) * 8;
    bf16x8 Bh = *reinterpret_cast<const bf16x8*>(&vhi[bidx]);
    bf16x8 Bl = *reinterpret_cast<const bf16x8*>(&vlo[bidx]);
    acc = __builtin_amdgcn_mfma_f32_16x16x32_bf16(ch.v, Bh, acc, 0, 0, 0);
    acc = __builtin_amdgcn_mfma_f32_16x16x32_bf16(cl.v, Bh, acc, 0, 0, 0);
    acc = __builtin_amdgcn_mfma_f32_16x16x32_bf16(ch.v, Bl, acc, 0, 0, 0);
  }
  int h = lr >> 1, s = lr & 1;
  float* dstp = (s == 0) ? ss : sd;
  #pragma unroll
  for (int r = 0; r < 4; ++r) {
    int row = row0 + lk * 4 + r;
    if (row < N) dstp[row * 8 + h] = acc[r];
  }
}

// Layer-1 x-aggregation: one wave per node. Weight lanes (head=lane>>3, li=lane&7)
// each compute TWO weights (edge slots li, li+8). Dst rows via wave-uniform scalar
// adj loads (readfirstlane'd bounds). 16 row-loads in flight per iteration.
__global__ __launch_bounds__(256) void k_agg1x(const u16* __restrict__ xb,
        const float* __restrict__ ss, const float* __restrict__ sd,
        const int* __restrict__ offs, const int* __restrict__ adj,
        u16* __restrict__ g, float* __restrict__ rs, int n) {
  int node = (blockIdx.x * 256 + threadIdx.x) >> 6;
  int lane = threadIdx.x & 63;
  if (node >= n) return;
  int head = lane >> 3, li = lane & 7;
  int beg = __builtin_amdgcn_readfirstlane(offs[node]);
  int end = __builtin_amdgcn_readfirstlane(offs[node + 1]);
  float sS = ss[node * 8 + head];
  f32x2 acc2[8] = {};
  float rsum = 0.f;
  const char* xbb = reinterpret_cast<const char*>(xb);
  for (int e = beg; e < end; e += 16) {
    int m = end - e; if (m > 16) m = 16;
    // per-lane weights for edge slots li and li+8 (clamped, zeroed past end)
    int i0 = li < m ? li : m - 1;
    int i1 = (li + 8) < m ? (li + 8) : m - 1;
    int dl0 = adj[e + i0];
    int dl1 = adj[e + i1];
    float z0 = sS + sd[(u32)dl0 * 8u + head];
    float z1 = sS + sd[(u32)dl1 * 8u + head];
    float w0 = __expf(-(z0 > 0.f ? z0 : 0.2f * z0));
    float w1 = __expf(-(z1 > 0.f ? z1 : 0.2f * z1));
    w0 = li < m ? w0 : 0.f;
    w1 = (li + 8) < m ? w1 : 0.f;
    rsum += w0 + w1;
    // uniform scalar dst indices -> 16 gathered feature words in flight
    u32 qv[16];
    #pragma unroll
    for (int i = 0; i < 16; i++) {
      int ii = i < m ? i : m - 1;
      int di = adj[e + ii];
      qv[i] = *reinterpret_cast<const u32*>(xbb + (u32)di * 256u + lane * 4u);
    }
    #pragma unroll
    for (int i = 0; i < 16; i++) {
      f32x2 xv = up2(qv[i]);
      #pragma unroll
      for (int h2 = 0; h2 < 8; h2++) {
        float wi = __shfl((i & 8) ? w1 : w0, h2 * 8 + (i & 7));
        acc2[h2] += (f32x2){wi, wi} * xv;
      }
    }
  }
  rsum += __shfl_xor(rsum, 1);
  rsum += __shfl_xor(rsum, 2);
  rsum += __shfl_xor(rsum, 4);
  if (li == 0) rs[node * 8 + head] = rsum;
  u32* gu = reinterpret_cast<u32*>(g);
  #pragma unroll
  for (int h2 = 0; h2 < 8; h2++)
    gu[((size_t)node * 8 + h2) * 64 + lane] = cvt_pk_bf16(acc2[h2].x, acc2[h2].y);
}

// Per-head GEMM: h1[row][head*64+c] = elu((g[row][head] @ W1[head])[c] / rsum)
__global__ __launch_bounds__(256) void k_mgemm1c(const u16* __restrict__ g,
        const u16* __restrict__ bhi, const u16* __restrict__ blo,
        const float* __restrict__ rs, u16* __restrict__ h1, int N) {
  int w = threadIdx.x >> 6, lane = threadIdx.x & 63;
  int lr = lane & 15, lk = lane >> 4;
  int head = blockIdx.y;
  int row0 = blockIdx.x * 64 + w * 16;
  f32x4 acc[4] = {};
  for (int ks = 0; ks < 4; ++ks) {
    int row = row0 + lr;
    int rc = row < N ? row : 0;
    bf16x8 Ah = *reinterpret_cast<const bf16x8*>(
        &g[((size_t)rc * 8 + head) * 128 + ks * 32 + lk * 8]);
    #pragma unroll
    for (int cf = 0; cf < 4; ++cf) {
      size_t bidx = ((size_t)((head * 4 + cf) * 4 + ks) * 64 + lane) * 8;
      bf16x8 Bh = *reinterpret_cast<const bf16x8*>(&bhi[bidx]);
      bf16x8 Bl = *reinterpret_cast<const bf16x8*>(&blo[bidx]);
      acc[cf] = __builtin_amdgcn_mfma_f32_16x16x32_bf16(Ah, Bh, acc[cf], 0, 0, 0);
      acc[cf] = __builtin_amdgcn_mfma_f32_16x16x32_bf16(Ah, Bl, acc[cf], 0, 0, 0);
    }
  }
  #pragma unroll
  for (int r = 0; r < 4; ++r) {
    int row = row0 + lk * 4 + r;
    if (row < N) {
      float inv = 1.f / rs[row * 8 + head];
      #pragma unroll
      for (int cf = 0; cf < 4; ++cf) {
        float v = acc[cf][r] * inv;
        v = v > 0.f ? v : expm1f(v);
        h1[(size_t)row * 512 + head * 64 + cf * 16 + lr] = (u16)cvt_pk_bf16(v, v);
      }
    }
  }
}

// GEMM2: bf16 [N,512] x [512,64] -> bf16 [N,64] + fused scores.
__global__ __launch_bounds__(256) void k_mgemm2(const u16* __restrict__ A,
        const u16* __restrict__ bhi, const u16* __restrict__ blo,
        const float* __restrict__ a2, u16* __restrict__ H2,
        float* __restrict__ ss, float* __restrict__ sdst, int N) {
  int w = threadIdx.x >> 6, lane = threadIdx.x & 63;
  int lr = lane & 15, lk = lane >> 4;
  int row0 = blockIdx.x * 128 + w * 32;
  f32x4 acc[2][4] = {};
  for (int ks = 0; ks < 16; ++ks) {
    bf16x8 Ah[2];
    #pragma unroll
    for (int rf = 0; rf < 2; ++rf) {
      int row = row0 + rf * 16 + lr;
      int rc = row < N ? row : 0;
      size_t aidx = (size_t)rc * 512 + ks * 32 + lk * 8;
      Ah[rf] = *reinterpret_cast<const bf16x8*>(&A[aidx]);
    }
    #pragma unroll
    for (int cf = 0; cf < 4; ++cf) {
      size_t bidx = ((size_t)(cf * 16 + ks) * 64 + lane) * 8;
      bf16x8 Bh = *reinterpret_cast<const bf16x8*>(&bhi[bidx]);
      bf16x8 Bl = *reinterpret_cast<const bf16x8*>(&blo[bidx]);
      #pragma unroll
      for (int rf = 0; rf < 2; ++rf) {
        acc[rf][cf] = __builtin_amdgcn_mfma_f32_16x16x32_bf16(Ah[rf], Bh, acc[rf][cf], 0, 0, 0);
        acc[rf][cf] = __builtin_amdgcn_mfma_f32_16x16x32_bf16(Ah[rf], Bl, acc[rf][cf], 0, 0, 0);
      }
    }
  }
  int hh = lr >> 3, jj = lr & 7;
  float a2s[4], a2d[4];
  #pragma unroll
  for (int cf = 0; cf < 4; ++cf) {
    int h = cf * 2 + hh;
    a2s[cf] = a2[h * 16 + jj];
    a2d[cf] = a2[h * 16 + 8 + jj];
  }
  #pragma unroll
  for (int rf = 0; rf < 2; ++rf) {
    #pragma unroll
    for (int r = 0; r < 4; ++r) {
      int row = row0 + rf * 16 + lk * 4 + r;
      if (row < N) {
        #pragma unroll
        for (int cf = 0; cf < 4; ++cf)
          H2[(size_t)row * 64 + cf * 16 + lr] =
              (u16)cvt_pk_bf16(acc[rf][cf][r], acc[rf][cf][r]);
      }
      float ps[4], pd[4];
      #pragma unroll
      for (int cf = 0; cf < 4; ++cf) {
        ps[cf] = acc[rf][cf][r] * a2s[cf];
        pd[cf] = acc[rf][cf][r] * a2d[cf];
      }
      #pragma unroll
      for (int m = 1; m < 8; m <<= 1) {
        #pragma unroll
        for (int cf = 0; cf < 4; ++cf) {
          ps[cf] += __shfl_xor(ps[cf], m);
          pd[cf] += __shfl_xor(pd[cf], m);
        }
      }
      if (jj == 0 && row < N) {
        #pragma unroll
        for (int cf = 0; cf < 4; ++cf) {
          int h = cf * 2 + hh;
          ss[row * 8 + h]   = ps[cf];
          sdst[row * 8 + h] = pd[cf];
        }
      }
    }
  }
}

// Layer-2 aggregation: one wave per node; lane = (li = lane>>3, fg = lane&7).
// 16 edge slots per iteration (2 per lane), uniform bounds, no shfl in loop.
__global__ __launch_bounds__(256) void k_agg2(const u16* __restrict__ H,
        const float* __restrict__ ss, const float* __restrict__ sd,
        const int* __restrict__ offs, const int* __restrict__ adj,
        float* __restrict__ outp, int n) {
  int node = (blockIdx.x * 256 + threadIdx.x) >> 6;
  int lane = threadIdx.x & 63;
  if (node >= n) return;
  int li = lane >> 3, fg = lane & 7;
  int beg = __builtin_amdgcn_readfirstlane(offs[node]);
  int end = __builtin_amdgcn_readfirstlane(offs[node + 1]);
  float sS = ss[node * 8 + fg];
  f32x2 acc2[4] = {};
  float rsum = 0.f;
  for (int e = beg; e < end; e += 16) {
    int m = end - e; if (m > 16) m = 16;
    int i0 = li < m ? li : m - 1;
    int i1 = (li + 8) < m ? (li + 8) : m - 1;
    u32 d0 = (u32)adj[e + i0];
    u32 d1 = (u32)adj[e + i1];
    uint4 rv0 = ld16(H, d0 * 128u + fg * 16u);
    uint4 rv1 = ld16(H, d1 * 128u + fg * 16u);
    float z0 = sS + sd[d0 * 8u + fg];
    float z1 = sS + sd[d1 * 8u + fg];
    float w0 = __expf(-(z0 > 0.f ? z0 : 0.2f * z0));
    float w1 = __expf(-(z1 > 0.f ? z1 : 0.2f * z1));
    w0 = li < m ? w0 : 0.f;
    w1 = (li + 8) < m ? w1 : 0.f;
    rsum += w0 + w1;
    f32x2 W0 = {w0, w0}, W1v = {w1, w1};
    acc2[0] += W0 * up2(rv0.x);
    acc2[1] += W0 * up2(rv0.y);
    acc2[2] += W0 * up2(rv0.z);
    acc2[3] += W0 * up2(rv0.w);
    acc2[0] += W1v * up2(rv1.x);
    acc2[1] += W1v * up2(rv1.y);
    acc2[2] += W1v * up2(rv1.z);
    acc2[3] += W1v * up2(rv1.w);
  }
  #pragma unroll
  for (int mask = 8; mask < 64; mask <<= 1) {
    rsum += __shfl_xor(rsum, mask);
    #pragma unroll
    for (int k = 0; k < 4; k++) {
      acc2[k].x += __shfl_xor(acc2[k].x, mask);
      acc2[k].y += __shfl_xor(acc2[k].y, mask);
    }
  }
  if (li == 0) {
    float inv = 1.f / rsum;
    float o[8];
    #pragma unroll
    for (int k = 0; k < 4; k++) {
      float v0 = acc2[k].x * inv, v1 = acc2[k].y * inv;
      o[2 * k]     = v0 > 0.f ? v0 : expm1f(v0);
      o[2 * k + 1] = v1 > 0.f ? v1 : expm1f(v1);
    }
    float4* Ov = reinterpret_cast<float4*>(outp);
    Ov[(size_t)node * 16 + fg * 2]     = make_float4(o[0], o[1], o[2], o[3]);
    Ov[(size_t)node * 16 + fg * 2 + 1] = make_float4(o[4], o[5], o[6], o[7]);
  }
}

extern "C" void kernel_launch(void* const* d_in, const int* in_sizes, int n_in,
                              void* d_out, int out_size, void* d_ws, size_t ws_size,
                              hipStream_t stream) {
  const float* x  = (const float*)d_in[0];
  const int*   ei = (const int*)d_in[1];
  const float* W1 = (const float*)d_in[2];
  const float* a1 = (const float*)d_in[3];
  const float* W2 = (const float*)d_in[4];
  const float* a2 = (const float*)d_in[5];
  float* out = (float*)d_out;

  int N = in_sizes[0] / TNFEAT;   // 50000
  int E = in_sizes[1] / 2;        // 850000
  const int* src = ei;
  const int* dst = ei + E;
  int NB = (N + 1023) / 1024;

  char* base = (char*)d_ws;
  size_t off = 0;
  auto take = [&](size_t bytes) { char* p = base + off; off = (off + bytes + 255) & ~(size_t)255; return p; };
  u16*   xb    = (u16*)take((size_t)N * TNFEAT * 2);       // 12.8 MB
  u16*   g     = (u16*)take((size_t)N * 8 * TNFEAT * 2);   // 102.4 MB
  u16*   h1    = (u16*)take((size_t)N * C1 * 2);           // 51.2 MB
  u16*   h2p   = (u16*)take((size_t)N * C2 * 2);           // 6.4 MB
  u16*   w1hi  = (u16*)take(65536 * 2);
  u16*   w1lo  = (u16*)take(65536 * 2);
  u16*   w2hi  = (u16*)take(32768 * 2);
  u16*   w2lo  = (u16*)take(32768 * 2);
  u16*   vhi   = (u16*)take(2048 * 2);
  u16*   vlo   = (u16*)take(2048 * 2);
  float* s1s   = (float*)take((size_t)N * 8 * 4);
  float* s1d   = (float*)take((size_t)N * 8 * 4);
  float* s2s   = (float*)take((size_t)N * 8 * 4);
  float* s2d   = (float*)take((size_t)N * 8 * 4);
  float* rs    = (float*)take((size_t)N * 8 * 4);
  int*   deg   = (int*)take((size_t)N * 4);
  int*   offs  = (int*)take((size_t)(N + 1) * 4);
  int*   cur   = (int*)take((size_t)N * 4);
  int*   loc   = (int*)take((size_t)N * 4);
  int*   bsum  = (int*)take(64 * 4);
  int*   adj   = (int*)take((size_t)E * 4);

  // CSR build (by src)
  hipLaunchKernelGGL(k_zero, dim3((N + 255) / 256), dim3(256), 0, stream, deg, N);
  hipLaunchKernelGGL(k_hist, dim3((E + 255) / 256), dim3(256), 0, stream, src, deg, E);
  hipLaunchKernelGGL(k_bscan1, dim3(NB), dim3(1024), 0, stream, deg, loc, bsum, N);
  hipLaunchKernelGGL(k_bscan2, dim3(1), dim3(64), 0, stream, bsum, NB);
  hipLaunchKernelGGL(k_offs, dim3(NB), dim3(1024), 0, stream, loc, bsum, deg, offs, cur, N);
  hipLaunchKernelGGL(k_fill, dim3((E + 255) / 256), dim3(256), 0, stream, src, dst, cur, adj, E);

  // Weight packing + score-projection vectors (single launch)
  hipLaunchKernelGGL(k_packAll, dim3(392), dim3(256), 0, stream,
                     W1, W2, a1, w1hi, w1lo, w2hi, w2lo, vhi, vlo);

  // Layer 1: xb + scores, x-space aggregation, per-head GEMM (rsum/elu fused)
  hipLaunchKernelGGL(k_xprep, dim3((N + 63) / 64), dim3(256), 0, stream,
                     x, vhi, vlo, xb, s1s, s1d, N);
  hipLaunchKernelGGL(k_agg1x, dim3((N + 3) / 4), dim3(256), 0, stream,
                     xb, s1s, s1d, offs, adj, g, rs, N);
  hipLaunchKernelGGL(k_mgemm1c, dim3((N + 63) / 64, 8), dim3(256), 0, stream,
                     g, w1hi, w1lo, rs, h1, N);

  // Layer 2
  hipLaunchKernelGGL(k_mgemm2, dim3((N + 127) / 128), dim3(256), 0, stream,
                     h1, w2hi, w2lo, a2, h2p, s2s, s2d, N);
  hipLaunchKernelGGL(k_agg2, dim3((N + 3) / 4), dim3(256), 0, stream,
                     h2p, s2s, s2d, offs, adj, out, N);
}

// Round 10
// 323.073 us; speedup vs baseline: 1.1393x; 1.0168x over previous
//
#include <hip/hip_runtime.h>
#include <math.h>

typedef unsigned int u32;
typedef unsigned short u16;
typedef __attribute__((ext_vector_type(8))) short bf16x8;
typedef __attribute__((ext_vector_type(4))) float f32x4;
typedef __attribute__((ext_vector_type(2))) float f32x2;

static constexpr int TNFEAT  = 128;
static constexpr int TNHEADS = 8;
static constexpr int C1      = 512;  // NHID*NHEADS
static constexpr int C2      = 64;   // NCLASS

__device__ inline float bf2f(u16 u) {
  union { u32 i; float f; } c; c.i = ((u32)u) << 16; return c.f;
}
__device__ inline float bitsf(u32 u) {
  union { u32 i; float f; } c; c.i = u; return c.f;
}
__device__ inline u16 f2bf(float f) {
  union { float f; u32 i; } c; c.f = f;
  u32 r = c.i + 0x7FFF + ((c.i >> 16) & 1);   // round-nearest-even
  return (u16)(r >> 16);
}
__device__ inline u32 cvt_pk_bf16(float lo, float hi) {
  u32 r;
  asm volatile("v_cvt_pk_bf16_f32 %0, %1, %2" : "=v"(r) : "v"(lo), "v"(hi));
  return r;
}
__device__ inline uint4 ld16(const u16* base, u32 byteoff) {
  return *reinterpret_cast<const uint4*>(reinterpret_cast<const char*>(base) + byteoff);
}
__device__ inline f32x2 up2(u32 q) {
  f32x2 p;
  p.x = bitsf(q << 16);
  p.y = bitsf(q & 0xffff0000u);
  return p;
}

__global__ void k_zero(int* __restrict__ p, int n) {
  int i = blockIdx.x * blockDim.x + threadIdx.x;
  if (i < n) p[i] = 0;
}

__global__ void k_hist(const int* __restrict__ src, int* __restrict__ deg, int E) {
  int i = blockIdx.x * blockDim.x + threadIdx.x;
  if (i < E) atomicAdd(&deg[src[i]], 1);
}

__global__ __launch_bounds__(1024) void k_bscan1(const int* __restrict__ deg,
                                                 int* __restrict__ loc,
                                                 int* __restrict__ bsum, int n) {
  __shared__ int sdata[1024];
  int t = threadIdx.x;
  int i = blockIdx.x * 1024 + t;
  int v = (i < n) ? deg[i] : 0;
  sdata[t] = v;
  __syncthreads();
  for (int ofs = 1; ofs < 1024; ofs <<= 1) {
    int tv = (t >= ofs) ? sdata[t - ofs] : 0;
    __syncthreads();
    sdata[t] += tv;
    __syncthreads();
  }
  if (i < n) loc[i] = sdata[t];
  if (t == 1023) bsum[blockIdx.x] = sdata[1023];
}

__global__ void k_bscan2(int* __restrict__ bsum, int nb) {
  int t = threadIdx.x;
  int v = (t < nb) ? bsum[t] : 0;
  #pragma unroll
  for (int ofs = 1; ofs < 64; ofs <<= 1) {
    int u = __shfl_up(v, ofs);
    if (t >= ofs) v += u;
  }
  if (t < nb) bsum[t] = v;
}

__global__ __launch_bounds__(1024) void k_offs(const int* __restrict__ loc,
                                               const int* __restrict__ bsum,
                                               const int* __restrict__ deg,
                                               int* __restrict__ offs,
                                               int* __restrict__ cur, int n) {
  int b = blockIdx.x;
  int i = b * 1024 + threadIdx.x;
  int base = (b > 0) ? bsum[b - 1] : 0;
  if (i < n) {
    int v = base + loc[i];
    offs[i + 1] = v;
    cur[i] = v - deg[i];
  }
  if (i == 0) offs[0] = 0;
}

__global__ void k_fill(const int* __restrict__ src, const int* __restrict__ dst,
                       int* __restrict__ cur, int* __restrict__ adj, int E) {
  int i = blockIdx.x * blockDim.x + threadIdx.x;
  if (i < E) {
    int p = atomicAdd(&cur[src[i]], 1);
    adj[p] = dst[i];
  }
}

// One launch: blocks [0,256) pack W1, [256,384) pack W2, [384,392) pack Vsd.
__global__ void k_packAll(const float* __restrict__ W1, const float* __restrict__ W2,
                          const float* __restrict__ a1,
                          u16* __restrict__ w1hi, u16* __restrict__ w1lo,
                          u16* __restrict__ w2hi, u16* __restrict__ w2lo,
                          u16* __restrict__ vhi, u16* __restrict__ vlo) {
  int b = blockIdx.x;
  if (b < 256) {
    int idx = b * 256 + threadIdx.x;   // 65536
    int j = idx & 7, lane = (idx >> 3) & 63, ks = (idx >> 9) & 3, cg = idx >> 11;
    int col = cg * 16 + (lane & 15);
    int k = ks * 32 + (lane >> 4) * 8 + j;
    float f = W1[((size_t)(col >> 6) * 128 + k) * 64 + (col & 63)];
    u16 h = f2bf(f);
    w1hi[idx] = h;
    w1lo[idx] = f2bf(f - bf2f(h));
  } else if (b < 384) {
    int idx = (b - 256) * 256 + threadIdx.x;   // 32768
    int j = idx & 7, lane = (idx >> 3) & 63, ks = (idx >> 9) & 15, cg = idx >> 13;
    int col = cg * 16 + (lane & 15);
    int k = ks * 32 + (lane >> 4) * 8 + j;
    float f = W2[((size_t)(col >> 3) * 512 + k) * 8 + (col & 7)];
    u16 h = f2bf(f);
    w2hi[idx] = h;
    w2lo[idx] = f2bf(f - bf2f(h));
  } else {
    int idx = (b - 384) * 256 + threadIdx.x;   // 2048
    int j = idx & 7, lane = (idx >> 3) & 63, ks = idx >> 9;
    int k = ks * 32 + (lane >> 4) * 8 + j;
    int c = lane & 15;
    int h = c >> 1, s = c & 1;
    const float* wrow = W1 + ((size_t)h * 128 + k) * 64;
    const float* av = a1 + h * 128 + s * 64;
    float dot = 0.f;
    #pragma unroll 8
    for (int f = 0; f < 64; f++) dot = fmaf(wrow[f], av[f], dot);
    u16 hb = f2bf(dot);
    vhi[idx] = hb;
    vlo[idx] = f2bf(dot - bf2f(hb));
  }
}

// x [N,128] fp32 -> xb bf16 [N,128]; scores [N,16] = x @ Vsd -> s1s/s1d (3-term MFMA)
__global__ __launch_bounds__(256) void k_xprep(const float* __restrict__ x,
        const u16* __restrict__ vhi, const u16* __restrict__ vlo,
        u16* __restrict__ xb, float* __restrict__ ss, float* __restrict__ sd, int N) {
  int w = threadIdx.x >> 6, lane = threadIdx.x & 63;
  int lr = lane & 15, lk = lane >> 4;
  int row0 = blockIdx.x * 64 + w * 16;
  f32x4 acc = {0.f, 0.f, 0.f, 0.f};
  for (int ks = 0; ks < 4; ++ks) {
    int row = row0 + lr;
    int rc = row < N ? row : 0;
    const float* ap = x + (size_t)rc * 128 + ks * 32 + lk * 8;
    float4 f0 = *reinterpret_cast<const float4*>(ap);
    float4 f1 = *reinterpret_cast<const float4*>(ap + 4);
    float fa[8] = {f0.x, f0.y, f0.z, f0.w, f1.x, f1.y, f1.z, f1.w};
    union { u32 u[4]; bf16x8 v; uint4 q; } ch, cl;
    #pragma unroll
    for (int p = 0; p < 4; ++p) {
      float e0 = fa[2 * p], e1 = fa[2 * p + 1];
      u32 h = cvt_pk_bf16(e0, e1);
      ch.u[p] = h;
      cl.u[p] = cvt_pk_bf16(e0 - bitsf(h << 16), e1 - bitsf(h & 0xffff0000u));
    }
    if (row < N)
      *reinterpret_cast<uint4*>(&xb[(size_t)row * 128 + ks * 32 + lk * 8]) = ch.q;
    size_t bidx = ((size_t)ks * 64 + lane) * 8;
    bf16x8 Bh = *reinterpret_cast<const bf16x8*>(&vhi[bidx]);
    bf16x8 Bl = *reinterpret_cast<const bf16x8*>(&vlo[bidx]);
    acc = __builtin_amdgcn_mfma_f32_16x16x32_bf16(ch.v, Bh, acc, 0, 0, 0);
    acc = __builtin_amdgcn_mfma_f32_16x16x32_bf16(cl.v, Bh, acc, 0, 0, 0);
    acc = __builtin_amdgcn_mfma_f32_16x16x32_bf16(ch.v, Bl, acc, 0, 0, 0);
  }
  int h = lr >> 1, s = lr & 1;
  float* dstp = (s == 0) ? ss : sd;
  #pragma unroll
  for (int r = 0; r < 4; ++r) {
    int row = row0 + lk * 4 + r;
    if (row < N) dstp[row * 8 + h] = acc[r];
  }
}

// Layer-1 x-aggregation: one wave per node. r7 structure (1 adj vector load +
// shfl-broadcast per 8-edge block) + 2-deep software pipeline:
//   adj prefetched 2 blocks ahead; gathers/sd issued 1 block ahead, hidden
//   under the previous block's 64-FMA accumulate.
__global__ __launch_bounds__(256) void k_agg1x(const u16* __restrict__ xb,
        const float* __restrict__ ss, const float* __restrict__ sd,
        const int* __restrict__ offs, const int* __restrict__ adj,
        u16* __restrict__ g, float* __restrict__ rs, int n) {
  int node = (blockIdx.x * 256 + threadIdx.x) >> 6;
  int lane = threadIdx.x & 63;
  if (node >= n) return;
  int head = lane >> 3, li = lane & 7;
  int beg = offs[node], end = offs[node + 1];
  float sS = ss[node * 8 + head];
  const char* xbb = reinterpret_cast<const char*>(xb);
  f32x2 acc2[8] = {};
  float rsum = 0.f;

  auto adjLoad = [&](int e) -> int {   // clamped per-lane slot load for block at e
    int mm = end - e; if (mm > 8) mm = 8;
    int ii = li < mm ? li : mm - 1;
    return adj[e + ii];
  };

  // prologue: block0 gathers issued; block1 adj issued.
  int dl1 = (beg + 8 < end) ? adjLoad(beg + 8) : 0;
  int dl0 = adjLoad(beg);
  float sdv = sd[(u32)dl0 * 8u + head];
  u32 qv[8];
  #pragma unroll
  for (int i = 0; i < 8; i++)
    qv[i] = *reinterpret_cast<const u32*>(xbb + (u32)__shfl(dl0, i) * 256u + lane * 4u);

  for (int e = beg; e < end; e += 8) {
    // 1. prefetch adj two blocks ahead
    int dlNN = (e + 16 < end) ? adjLoad(e + 16) : 0;
    // 2. current weights (sdv issued last iter)
    int mc = end - e; if (mc > 8) mc = 8;
    float z = sS + sdv;
    float w = __expf(-(z > 0.f ? z : 0.2f * z));
    if (li >= mc) w = 0.f;
    rsum += w;
    // 3. issue next block's gathers + sd (dl1 loaded one iter ago)
    bool hn = (e + 8) < end;
    u32 qvN[8];
    float sdN = 0.f;
    if (hn) {
      #pragma unroll
      for (int i = 0; i < 8; i++)
        qvN[i] = *reinterpret_cast<const u32*>(xbb + (u32)__shfl(dl1, i) * 256u + lane * 4u);
      sdN = sd[(u32)dl1 * 8u + head];
    }
    // 4. accumulate current block (hides qvN/sdN latency)
    #pragma unroll
    for (int i = 0; i < 8; i++) {
      f32x2 xv = up2(qv[i]);
      #pragma unroll
      for (int h2 = 0; h2 < 8; h2++) {
        float wi = __shfl(w, h2 * 8 + i);
        acc2[h2] += (f32x2){wi, wi} * xv;
      }
    }
    // 5. shift pipeline state
    if (hn) {
      #pragma unroll
      for (int i = 0; i < 8; i++) qv[i] = qvN[i];
      sdv = sdN;
    }
    dl1 = dlNN;
  }
  rsum += __shfl_xor(rsum, 1);
  rsum += __shfl_xor(rsum, 2);
  rsum += __shfl_xor(rsum, 4);
  if (li == 0) rs[node * 8 + head] = rsum;
  u32* gu = reinterpret_cast<u32*>(g);
  #pragma unroll
  for (int h2 = 0; h2 < 8; h2++)
    gu[((size_t)node * 8 + h2) * 64 + lane] = cvt_pk_bf16(acc2[h2].x, acc2[h2].y);
}

// Per-head GEMM: h1[row][head*64+c] = elu((g[row][head] @ W1[head])[c] / rsum)
__global__ __launch_bounds__(256) void k_mgemm1c(const u16* __restrict__ g,
        const u16* __restrict__ bhi, const u16* __restrict__ blo,
        const float* __restrict__ rs, u16* __restrict__ h1, int N) {
  int w = threadIdx.x >> 6, lane = threadIdx.x & 63;
  int lr = lane & 15, lk = lane >> 4;
  int head = blockIdx.y;
  int row0 = blockIdx.x * 64 + w * 16;
  f32x4 acc[4] = {};
  for (int ks = 0; ks < 4; ++ks) {
    int row = row0 + lr;
    int rc = row < N ? row : 0;
    bf16x8 Ah = *reinterpret_cast<const bf16x8*>(
        &g[((size_t)rc * 8 + head) * 128 + ks * 32 + lk * 8]);
    #pragma unroll
    for (int cf = 0; cf < 4; ++cf) {
      size_t bidx = ((size_t)((head * 4 + cf) * 4 + ks) * 64 + lane) * 8;
      bf16x8 Bh = *reinterpret_cast<const bf16x8*>(&bhi[bidx]);
      bf16x8 Bl = *reinterpret_cast<const bf16x8*>(&blo[bidx]);
      acc[cf] = __builtin_amdgcn_mfma_f32_16x16x32_bf16(Ah, Bh, acc[cf], 0, 0, 0);
      acc[cf] = __builtin_amdgcn_mfma_f32_16x16x32_bf16(Ah, Bl, acc[cf], 0, 0, 0);
    }
  }
  #pragma unroll
  for (int r = 0; r < 4; ++r) {
    int row = row0 + lk * 4 + r;
    if (row < N) {
      float inv = 1.f / rs[row * 8 + head];
      #pragma unroll
      for (int cf = 0; cf < 4; ++cf) {
        float v = acc[cf][r] * inv;
        v = v > 0.f ? v : expm1f(v);
        h1[(size_t)row * 512 + head * 64 + cf * 16 + lr] = (u16)cvt_pk_bf16(v, v);
      }
    }
  }
}

// GEMM2: bf16 [N,512] x [512,64] -> bf16 [N,64] + fused scores.
__global__ __launch_bounds__(256) void k_mgemm2(const u16* __restrict__ A,
        const u16* __restrict__ bhi, const u16* __restrict__ blo,
        const float* __restrict__ a2, u16* __restrict__ H2,
        float* __restrict__ ss, float* __restrict__ sdst, int N) {
  int w = threadIdx.x >> 6, lane = threadIdx.x & 63;
  int lr = lane & 15, lk = lane >> 4;
  int row0 = blockIdx.x * 128 + w * 32;
  f32x4 acc[2][4] = {};
  for (int ks = 0; ks < 16; ++ks) {
    bf16x8 Ah[2];
    #pragma unroll
    for (int rf = 0; rf < 2; ++rf) {
      int row = row0 + rf * 16 + lr;
      int rc = row < N ? row : 0;
      size_t aidx = (size_t)rc * 512 + ks * 32 + lk * 8;
      Ah[rf] = *reinterpret_cast<const bf16x8*>(&A[aidx]);
    }
    #pragma unroll
    for (int cf = 0; cf < 4; ++cf) {
      size_t bidx = ((size_t)(cf * 16 + ks) * 64 + lane) * 8;
      bf16x8 Bh = *reinterpret_cast<const bf16x8*>(&bhi[bidx]);
      bf16x8 Bl = *reinterpret_cast<const bf16x8*>(&blo[bidx]);
      #pragma unroll
      for (int rf = 0; rf < 2; ++rf) {
        acc[rf][cf] = __builtin_amdgcn_mfma_f32_16x16x32_bf16(Ah[rf], Bh, acc[rf][cf], 0, 0, 0);
        acc[rf][cf] = __builtin_amdgcn_mfma_f32_16x16x32_bf16(Ah[rf], Bl, acc[rf][cf], 0, 0, 0);
      }
    }
  }
  int hh = lr >> 3, jj = lr & 7;
  float a2s[4], a2d[4];
  #pragma unroll
  for (int cf = 0; cf < 4; ++cf) {
    int h = cf * 2 + hh;
    a2s[cf] = a2[h * 16 + jj];
    a2d[cf] = a2[h * 16 + 8 + jj];
  }
  #pragma unroll
  for (int rf = 0; rf < 2; ++rf) {
    #pragma unroll
    for (int r = 0; r < 4; ++r) {
      int row = row0 + rf * 16 + lk * 4 + r;
      if (row < N) {
        #pragma unroll
        for (int cf = 0; cf < 4; ++cf)
          H2[(size_t)row * 64 + cf * 16 + lr] =
              (u16)cvt_pk_bf16(acc[rf][cf][r], acc[rf][cf][r]);
      }
      float ps[4], pd[4];
      #pragma unroll
      for (int cf = 0; cf < 4; ++cf) {
        ps[cf] = acc[rf][cf][r] * a2s[cf];
        pd[cf] = acc[rf][cf][r] * a2d[cf];
      }
      #pragma unroll
      for (int m = 1; m < 8; m <<= 1) {
        #pragma unroll
        for (int cf = 0; cf < 4; ++cf) {
          ps[cf] += __shfl_xor(ps[cf], m);
          pd[cf] += __shfl_xor(pd[cf], m);
        }
      }
      if (jj == 0 && row < N) {
        #pragma unroll
        for (int cf = 0; cf < 4; ++cf) {
          int h = cf * 2 + hh;
          ss[row * 8 + h]   = ps[cf];
          sdst[row * 8 + h] = pd[cf];
        }
      }
    }
  }
}

// Layer-2 aggregation: one wave per node; lane = (li = lane>>3, fg = lane&7).
// 16 edge slots per iteration (2 per lane), 2-deep pipelined prefetch.
__global__ __launch_bounds__(256) void k_agg2(const u16* __restrict__ H,
        const float* __restrict__ ss, const float* __restrict__ sd,
        const int* __restrict__ offs, const int* __restrict__ adj,
        float* __restrict__ outp, int n) {
  int node = (blockIdx.x * 256 + threadIdx.x) >> 6;
  int lane = threadIdx.x & 63;
  if (node >= n) return;
  int li = lane >> 3, fg = lane & 7;
  int beg = offs[node], end = offs[node + 1];
  float sS = ss[node * 8 + fg];
  f32x2 acc2[4] = {};
  float rsum = 0.f;

  auto adj2 = [&](int e, int slot) -> u32 {
    int mm = end - e; if (mm > 16) mm = 16;
    int ii = slot < mm ? slot : mm - 1;
    return (u32)adj[e + ii];
  };

  // prologue: block0 loads issued; block1 adj issued.
  u32 d0n = 0, d1n = 0;
  if (beg + 16 < end) { d0n = adj2(beg + 16, li); d1n = adj2(beg + 16, li + 8); }
  u32 d0 = adj2(beg, li), d1 = adj2(beg, li + 8);
  uint4 rv0 = ld16(H, d0 * 128u + fg * 16u);
  uint4 rv1 = ld16(H, d1 * 128u + fg * 16u);
  float sd0 = sd[d0 * 8u + fg], sd1 = sd[d1 * 8u + fg];

  for (int e = beg; e < end; e += 16) {
    u32 d0nn = 0, d1nn = 0;
    if (e + 32 < end) { d0nn = adj2(e + 32, li); d1nn = adj2(e + 32, li + 8); }
    int mc = end - e; if (mc > 16) mc = 16;
    float z0 = sS + sd0, z1 = sS + sd1;
    float w0 = __expf(-(z0 > 0.f ? z0 : 0.2f * z0));
    float w1 = __expf(-(z1 > 0.f ? z1 : 0.2f * z1));
    w0 = li < mc ? w0 : 0.f;
    w1 = (li + 8) < mc ? w1 : 0.f;
    rsum += w0 + w1;
    // issue next block's loads (adj arrived one iter ago)
    bool hn = (e + 16) < end;
    uint4 rv0N = {}, rv1N = {};
    float sd0N = 0.f, sd1N = 0.f;
    if (hn) {
      rv0N = ld16(H, d0n * 128u + fg * 16u);
      rv1N = ld16(H, d1n * 128u + fg * 16u);
      sd0N = sd[d0n * 8u + fg];
      sd1N = sd[d1n * 8u + fg];
    }
    // accumulate current
    f32x2 W0 = {w0, w0}, W1v = {w1, w1};
    acc2[0] += W0 * up2(rv0.x);
    acc2[1] += W0 * up2(rv0.y);
    acc2[2] += W0 * up2(rv0.z);
    acc2[3] += W0 * up2(rv0.w);
    acc2[0] += W1v * up2(rv1.x);
    acc2[1] += W1v * up2(rv1.y);
    acc2[2] += W1v * up2(rv1.z);
    acc2[3] += W1v * up2(rv1.w);
    // shift
    if (hn) { rv0 = rv0N; rv1 = rv1N; sd0 = sd0N; sd1 = sd1N; }
    d0n = d0nn; d1n = d1nn;
  }
  #pragma unroll
  for (int mask = 8; mask < 64; mask <<= 1) {
    rsum += __shfl_xor(rsum, mask);
    #pragma unroll
    for (int k = 0; k < 4; k++) {
      acc2[k].x += __shfl_xor(acc2[k].x, mask);
      acc2[k].y += __shfl_xor(acc2[k].y, mask);
    }
  }
  if (li == 0) {
    float inv = 1.f / rsum;
    float o[8];
    #pragma unroll
    for (int k = 0; k < 4; k++) {
      float v0 = acc2[k].x * inv, v1 = acc2[k].y * inv;
      o[2 * k]     = v0 > 0.f ? v0 : expm1f(v0);
      o[2 * k + 1] = v1 > 0.f ? v1 : expm1f(v1);
    }
    float4* Ov = reinterpret_cast<float4*>(outp);
    Ov[(size_t)node * 16 + fg * 2]     = make_float4(o[0], o[1], o[2], o[3]);
    Ov[(size_t)node * 16 + fg * 2 + 1] = make_float4(o[4], o[5], o[6], o[7]);
  }
}

extern "C" void kernel_launch(void* const* d_in, const int* in_sizes, int n_in,
                              void* d_out, int out_size, void* d_ws, size_t ws_size,
                              hipStream_t stream) {
  const float* x  = (const float*)d_in[0];
  const int*   ei = (const int*)d_in[1];
  const float* W1 = (const float*)d_in[2];
  const float* a1 = (const float*)d_in[3];
  const float* W2 = (const float*)d_in[4];
  const float* a2 = (const float*)d_in[5];
  float* out = (float*)d_out;

  int N = in_sizes[0] / TNFEAT;   // 50000
  int E = in_sizes[1] / 2;        // 850000
  const int* src = ei;
  const int* dst = ei + E;
  int NB = (N + 1023) / 1024;

  char* base = (char*)d_ws;
  size_t off = 0;
  auto take = [&](size_t bytes) { char* p = base + off; off = (off + bytes + 255) & ~(size_t)255; return p; };
  u16*   xb    = (u16*)take((size_t)N * TNFEAT * 2);       // 12.8 MB
  u16*   g     = (u16*)take((size_t)N * 8 * TNFEAT * 2);   // 102.4 MB
  u16*   h1    = (u16*)take((size_t)N * C1 * 2);           // 51.2 MB
  u16*   h2p   = (u16*)take((size_t)N * C2 * 2);           // 6.4 MB
  u16*   w1hi  = (u16*)take(65536 * 2);
  u16*   w1lo  = (u16*)take(65536 * 2);
  u16*   w2hi  = (u16*)take(32768 * 2);
  u16*   w2lo  = (u16*)take(32768 * 2);
  u16*   vhi   = (u16*)take(2048 * 2);
  u16*   vlo   = (u16*)take(2048 * 2);
  float* s1s   = (float*)take((size_t)N * 8 * 4);
  float* s1d   = (float*)take((size_t)N * 8 * 4);
  float* s2s   = (float*)take((size_t)N * 8 * 4);
  float* s2d   = (float*)take((size_t)N * 8 * 4);
  float* rs    = (float*)take((size_t)N * 8 * 4);
  int*   deg   = (int*)take((size_t)N * 4);
  int*   offs  = (int*)take((size_t)(N + 1) * 4);
  int*   cur   = (int*)take((size_t)N * 4);
  int*   loc   = (int*)take((size_t)N * 4);
  int*   bsum  = (int*)take(64 * 4);
  int*   adj   = (int*)take((size_t)E * 4);

  // CSR build (by src)
  hipLaunchKernelGGL(k_zero, dim3((N + 255) / 256), dim3(256), 0, stream, deg, N);
  hipLaunchKernelGGL(k_hist, dim3((E + 255) / 256), dim3(256), 0, stream, src, deg, E);
  hipLaunchKernelGGL(k_bscan1, dim3(NB), dim3(1024), 0, stream, deg, loc, bsum, N);
  hipLaunchKernelGGL(k_bscan2, dim3(1), dim3(64), 0, stream, bsum, NB);
  hipLaunchKernelGGL(k_offs, dim3(NB), dim3(1024), 0, stream, loc, bsum, deg, offs, cur, N);
  hipLaunchKernelGGL(k_fill, dim3((E + 255) / 256), dim3(256), 0, stream, src, dst, cur, adj, E);

  // Weight packing + score-projection vectors (single launch)
  hipLaunchKernelGGL(k_packAll, dim3(392), dim3(256), 0, stream,
                     W1, W2, a1, w1hi, w1lo, w2hi, w2lo, vhi, vlo);

  // Layer 1: xb + scores, x-space aggregation, per-head GEMM (rsum/elu fused)
  hipLaunchKernelGGL(k_xprep, dim3((N + 63) / 64), dim3(256), 0, stream,
                     x, vhi, vlo, xb, s1s, s1d, N);
  hipLaunchKernelGGL(k_agg1x, dim3((N + 3) / 4), dim3(256), 0, stream,
                     xb, s1s, s1d, offs, adj, g, rs, N);
  hipLaunchKernelGGL(k_mgemm1c, dim3((N + 63) / 64, 8), dim3(256), 0, stream,
                     g, w1hi, w1lo, rs, h1, N);

  // Layer 2
  hipLaunchKernelGGL(k_mgemm2, dim3((N + 127) / 128), dim3(256), 0, stream,
                     h1, w2hi, w2lo, a2, h2p, s2s, s2d, N);
  hipLaunchKernelGGL(k_agg2, dim3((N + 3) / 4), dim3(256), 0, stream,
                     h2p, s2s, s2d, offs, adj, out, N);
}

// Round 11
// 261.394 us; speedup vs baseline: 1.4081x; 1.2360x over previous
//
#include <hip/hip_runtime.h>
#include <math.h>

typedef unsigned int u32;
typedef unsigned short u16;
typedef __attribute__((ext_vector_type(8))) short bf16x8;
typedef __attribute__((ext_vector_type(4))) float f32x4;
typedef __attribute__((ext_vector_type(2))) float f32x2;

static constexpr int TNFEAT  = 128;
static constexpr int TNHEADS = 8;
static constexpr int C1      = 512;  // NHID*NHEADS
static constexpr int C2      = 64;   // NCLASS

__device__ inline float bf2f(u16 u) {
  union { u32 i; float f; } c; c.i = ((u32)u) << 16; return c.f;
}
__device__ inline float bitsf(u32 u) {
  union { u32 i; float f; } c; c.i = u; return c.f;
}
__device__ inline u16 f2bf(float f) {
  union { float f; u32 i; } c; c.f = f;
  u32 r = c.i + 0x7FFF + ((c.i >> 16) & 1);   // round-nearest-even
  return (u16)(r >> 16);
}
__device__ inline u32 cvt_pk_bf16(float lo, float hi) {
  u32 r;
  asm volatile("v_cvt_pk_bf16_f32 %0, %1, %2" : "=v"(r) : "v"(lo), "v"(hi));
  return r;
}
__device__ inline uint4 ld16(const u16* base, u32 byteoff) {
  return *reinterpret_cast<const uint4*>(reinterpret_cast<const char*>(base) + byteoff);
}
__device__ inline f32x2 up2(u32 q) {
  f32x2 p;
  p.x = bitsf(q << 16);
  p.y = bitsf(q & 0xffff0000u);
  return p;
}
// wave-uniform broadcast from compile-time lane via readlane (VALU/SGPR, no LDS pipe)
__device__ inline int rdl_i(int v, int l) { return __builtin_amdgcn_readlane(v, l); }
__device__ inline float rdl_f(float v, int l) {
  union { float f; int i; } c; c.f = v;
  union { int i; float f; } d; d.i = __builtin_amdgcn_readlane(c.i, l);
  return d.f;
}

__global__ void k_zero(int* __restrict__ p, int n) {
  int i = blockIdx.x * blockDim.x + threadIdx.x;
  if (i < n) p[i] = 0;
}

__global__ void k_hist(const int* __restrict__ src, int* __restrict__ deg, int E) {
  int i = blockIdx.x * blockDim.x + threadIdx.x;
  if (i < E) atomicAdd(&deg[src[i]], 1);
}

__global__ __launch_bounds__(1024) void k_bscan1(const int* __restrict__ deg,
                                                 int* __restrict__ loc,
                                                 int* __restrict__ bsum, int n) {
  __shared__ int sdata[1024];
  int t = threadIdx.x;
  int i = blockIdx.x * 1024 + t;
  int v = (i < n) ? deg[i] : 0;
  sdata[t] = v;
  __syncthreads();
  for (int ofs = 1; ofs < 1024; ofs <<= 1) {
    int tv = (t >= ofs) ? sdata[t - ofs] : 0;
    __syncthreads();
    sdata[t] += tv;
    __syncthreads();
  }
  if (i < n) loc[i] = sdata[t];
  if (t == 1023) bsum[blockIdx.x] = sdata[1023];
}

__global__ void k_bscan2(int* __restrict__ bsum, int nb) {
  int t = threadIdx.x;
  int v = (t < nb) ? bsum[t] : 0;
  #pragma unroll
  for (int ofs = 1; ofs < 64; ofs <<= 1) {
    int u = __shfl_up(v, ofs);
    if (t >= ofs) v += u;
  }
  if (t < nb) bsum[t] = v;
}

__global__ __launch_bounds__(1024) void k_offs(const int* __restrict__ loc,
                                               const int* __restrict__ bsum,
                                               const int* __restrict__ deg,
                                               int* __restrict__ offs,
                                               int* __restrict__ cur, int n) {
  int b = blockIdx.x;
  int i = b * 1024 + threadIdx.x;
  int base = (b > 0) ? bsum[b - 1] : 0;
  if (i < n) {
    int v = base + loc[i];
    offs[i + 1] = v;
    cur[i] = v - deg[i];
  }
  if (i == 0) offs[0] = 0;
}

__global__ void k_fill(const int* __restrict__ src, const int* __restrict__ dst,
                       int* __restrict__ cur, int* __restrict__ adj, int E) {
  int i = blockIdx.x * blockDim.x + threadIdx.x;
  if (i < E) {
    int p = atomicAdd(&cur[src[i]], 1);
    adj[p] = dst[i];
  }
}

// One launch: blocks [0,256) pack W1, [256,384) pack W2, [384,392) pack Vsd.
__global__ void k_packAll(const float* __restrict__ W1, const float* __restrict__ W2,
                          const float* __restrict__ a1,
                          u16* __restrict__ w1hi, u16* __restrict__ w1lo,
                          u16* __restrict__ w2hi, u16* __restrict__ w2lo,
                          u16* __restrict__ vhi, u16* __restrict__ vlo) {
  int b = blockIdx.x;
  if (b < 256) {
    int idx = b * 256 + threadIdx.x;   // 65536
    int j = idx & 7, lane = (idx >> 3) & 63, ks = (idx >> 9) & 3, cg = idx >> 11;
    int col = cg * 16 + (lane & 15);
    int k = ks * 32 + (lane >> 4) * 8 + j;
    float f = W1[((size_t)(col >> 6) * 128 + k) * 64 + (col & 63)];
    u16 h = f2bf(f);
    w1hi[idx] = h;
    w1lo[idx] = f2bf(f - bf2f(h));
  } else if (b < 384) {
    int idx = (b - 256) * 256 + threadIdx.x;   // 32768
    int j = idx & 7, lane = (idx >> 3) & 63, ks = (idx >> 9) & 15, cg = idx >> 13;
    int col = cg * 16 + (lane & 15);
    int k = ks * 32 + (lane >> 4) * 8 + j;
    float f = W2[((size_t)(col >> 3) * 512 + k) * 8 + (col & 7)];
    u16 h = f2bf(f);
    w2hi[idx] = h;
    w2lo[idx] = f2bf(f - bf2f(h));
  } else {
    int idx = (b - 384) * 256 + threadIdx.x;   // 2048
    int j = idx & 7, lane = (idx >> 3) & 63, ks = idx >> 9;
    int k = ks * 32 + (lane >> 4) * 8 + j;
    int c = lane & 15;
    int h = c >> 1, s = c & 1;
    const float* wrow = W1 + ((size_t)h * 128 + k) * 64;
    const float* av = a1 + h * 128 + s * 64;
    float dot = 0.f;
    #pragma unroll 8
    for (int f = 0; f < 64; f++) dot = fmaf(wrow[f], av[f], dot);
    u16 hb = f2bf(dot);
    vhi[idx] = hb;
    vlo[idx] = f2bf(dot - bf2f(hb));
  }
}

// x [N,128] fp32 -> xb bf16 [N,128]; scores [N,16] = x @ Vsd -> s1s/s1d (3-term MFMA)
__global__ __launch_bounds__(256) void k_xprep(const float* __restrict__ x,
        const u16* __restrict__ vhi, const u16* __restrict__ vlo,
        u16* __restrict__ xb, float* __restrict__ ss, float* __restrict__ sd, int N) {
  int w = threadIdx.x >> 6, lane = threadIdx.x & 63;
  int lr = lane & 15, lk = lane >> 4;
  int row0 = blockIdx.x * 64 + w * 16;
  f32x4 acc = {0.f, 0.f, 0.f, 0.f};
  for (int ks = 0; ks < 4; ++ks) {
    int row = row0 + lr;
    int rc = row < N ? row : 0;
    const float* ap = x + (size_t)rc * 128 + ks * 32 + lk * 8;
    float4 f0 = *reinterpret_cast<const float4*>(ap);
    float4 f1 = *reinterpret_cast<const float4*>(ap + 4);
    float fa[8] = {f0.x, f0.y, f0.z, f0.w, f1.x, f1.y, f1.z, f1.w};
    union { u32 u[4]; bf16x8 v; uint4 q; } ch, cl;
    #pragma unroll
    for (int p = 0; p < 4; ++p) {
      float e0 = fa[2 * p], e1 = fa[2 * p + 1];
      u32 h = cvt_pk_bf16(e0, e1);
      ch.u[p] = h;
      cl.u[p] = cvt_pk_bf16(e0 - bitsf(h << 16), e1 - bitsf(h & 0xffff0000u));
    }
    if (row < N)
      *reinterpret_cast<uint4*>(&xb[(size_t)row * 128 + ks * 32 + lk * 8]) = ch.q;
    size_t bidx = ((size_t)ks * 64 + lane) * 8;
    bf16x8 Bh = *reinterpret_cast<const bf16x8*>(&vhi[bidx]);
    bf16x8 Bl = *reinterpret_cast<const bf16x8*>(&vlo[bidx]);
    acc = __builtin_amdgcn_mfma_f32_16x16x32_bf16(ch.v, Bh, acc, 0, 0, 0);
    acc = __builtin_amdgcn_mfma_f32_16x16x32_bf16(cl.v, Bh, acc, 0, 0, 0);
    acc = __builtin_amdgcn_mfma_f32_16x16x32_bf16(ch.v, Bl, acc, 0, 0, 0);
  }
  int h = lr >> 1, s = lr & 1;
  float* dstp = (s == 0) ? ss : sd;
  #pragma unroll
  for (int r = 0; r < 4; ++r) {
    int row = row0 + lk * 4 + r;
    if (row < N) dstp[row * 8 + h] = acc[r];
  }
}

// Layer-1 x-aggregation (r7 structure): one wave per node.
// Weight lanes (head=lane>>3, li=lane&7) each compute ONE weight (edge li, own head).
// All broadcasts via v_readlane (compile-time lanes) -> SGPR: dst indices become
// scalar bases (saddr gathers), weights feed pk_fma as scalars. No LDS-pipe ops.
__global__ __launch_bounds__(256) void k_agg1x(const u16* __restrict__ xb,
        const float* __restrict__ ss, const float* __restrict__ sd,
        const int* __restrict__ offs, const int* __restrict__ adj,
        u16* __restrict__ g, float* __restrict__ rs, int n) {
  int node = (blockIdx.x * 256 + threadIdx.x) >> 6;
  int lane = threadIdx.x & 63;
  if (node >= n) return;
  int head = lane >> 3, li = lane & 7;
  int beg = offs[node], end = offs[node + 1];
  float sS = ss[node * 8 + head];
  const char* xbb = reinterpret_cast<const char*>(xb);
  f32x2 acc2[8] = {};
  float rsum = 0.f;
  int e = beg;
  for (; e + 8 <= end; e += 8) {
    int dl = adj[e + li];
    float z = sS + sd[(u32)dl * 8u + head];
    float w = __expf(-(z > 0.f ? z : 0.2f * z));
    rsum += w;
    u32 qv[8];
    #pragma unroll
    for (int i = 0; i < 8; i++) {
      u32 di = (u32)rdl_i(dl, i);                  // SGPR dst index
      qv[i] = *reinterpret_cast<const u32*>(xbb + di * 256u + lane * 4u);
    }
    #pragma unroll
    for (int i = 0; i < 8; i++) {
      f32x2 xv = up2(qv[i]);
      #pragma unroll
      for (int h2 = 0; h2 < 8; h2++) {
        float wi = rdl_f(w, h2 * 8 + i);           // SGPR weight
        acc2[h2] += (f32x2){wi, wi} * xv;
      }
    }
  }
  if (e < end) {
    int m = end - e;
    int lic = li < m ? li : m - 1;
    int dl = adj[e + lic];
    float z = sS + sd[(u32)dl * 8u + head];
    float w = __expf(-(z > 0.f ? z : 0.2f * z));
    if (li >= m) w = 0.f;
    rsum += w;
    u32 qv[8];
    #pragma unroll
    for (int i = 0; i < 8; i++) {
      if (i < m) {
        u32 di = (u32)rdl_i(dl, i);
        qv[i] = *reinterpret_cast<const u32*>(xbb + di * 256u + lane * 4u);
      }
    }
    #pragma unroll
    for (int i = 0; i < 8; i++) {
      if (i < m) {
        f32x2 xv = up2(qv[i]);
        #pragma unroll
        for (int h2 = 0; h2 < 8; h2++) {
          float wi = rdl_f(w, h2 * 8 + i);
          acc2[h2] += (f32x2){wi, wi} * xv;
        }
      }
    }
  }
  rsum += __shfl_xor(rsum, 1);
  rsum += __shfl_xor(rsum, 2);
  rsum += __shfl_xor(rsum, 4);
  if (li == 0) rs[node * 8 + head] = rsum;
  u32* gu = reinterpret_cast<u32*>(g);
  #pragma unroll
  for (int h2 = 0; h2 < 8; h2++)
    gu[((size_t)node * 8 + h2) * 64 + lane] = cvt_pk_bf16(acc2[h2].x, acc2[h2].y);
}

// Fused GEMM1-apply + GEMM2 + scores: block = 32 rows.
// Phase A: wave w computes heads 2w,2w+1 -> elu(g@W1/rsum) -> LDS h1 tile (bf16).
// Phase B: wave w computes output cols w*16..+16 = heads 2w,2w+1 of GEMM2 + scores.
__global__ __launch_bounds__(256) void k_gemm12(const u16* __restrict__ g,
        const u16* __restrict__ w1h, const u16* __restrict__ w1l,
        const float* __restrict__ rs,
        const u16* __restrict__ w2h, const u16* __restrict__ w2l,
        const float* __restrict__ a2,
        u16* __restrict__ h2p, float* __restrict__ ss2, float* __restrict__ sd2,
        int N) {
  __shared__ u16 h1t[32][516];   // 516 = 512 + 4 pad (2-way-free LDS banks)
  int w = threadIdx.x >> 6, lane = threadIdx.x & 63;
  int lr = lane & 15, lk = lane >> 4;
  int row0 = blockIdx.x * 32;
  // ---- Phase A ----
  for (int hh = 0; hh < 2; ++hh) {
    int head = 2 * w + hh;
    f32x4 acc[2][4] = {};
    for (int ks = 0; ks < 4; ++ks) {
      bf16x8 Ah[2];
      #pragma unroll
      for (int rf = 0; rf < 2; ++rf) {
        int row = row0 + rf * 16 + lr;
        int rc = row < N ? row : 0;
        Ah[rf] = *reinterpret_cast<const bf16x8*>(
            &g[((size_t)rc * 8 + head) * 128 + ks * 32 + lk * 8]);
      }
      #pragma unroll
      for (int cf = 0; cf < 4; ++cf) {
        size_t bidx = ((size_t)((head * 4 + cf) * 4 + ks) * 64 + lane) * 8;
        bf16x8 Bh = *reinterpret_cast<const bf16x8*>(&w1h[bidx]);
        bf16x8 Bl = *reinterpret_cast<const bf16x8*>(&w1l[bidx]);
        #pragma unroll
        for (int rf = 0; rf < 2; ++rf) {
          acc[rf][cf] = __builtin_amdgcn_mfma_f32_16x16x32_bf16(Ah[rf], Bh, acc[rf][cf], 0, 0, 0);
          acc[rf][cf] = __builtin_amdgcn_mfma_f32_16x16x32_bf16(Ah[rf], Bl, acc[rf][cf], 0, 0, 0);
        }
      }
    }
    #pragma unroll
    for (int rf = 0; rf < 2; ++rf) {
      #pragma unroll
      for (int r = 0; r < 4; ++r) {
        int srow = rf * 16 + lk * 4 + r;
        int row = row0 + srow;
        float inv = 1.f / rs[(size_t)(row < N ? row : 0) * 8 + head];
        #pragma unroll
        for (int cf = 0; cf < 4; ++cf) {
          float v = acc[rf][cf][r] * inv;
          v = v > 0.f ? v : expm1f(v);
          h1t[srow][head * 64 + cf * 16 + lr] = (u16)cvt_pk_bf16(v, v);
        }
      }
    }
  }
  __syncthreads();
  // ---- Phase B ----
  f32x4 accB[2] = {};
  for (int ks = 0; ks < 16; ++ks) {
    bf16x8 Ah[2];
    #pragma unroll
    for (int rf = 0; rf < 2; ++rf)
      Ah[rf] = *reinterpret_cast<const bf16x8*>(&h1t[rf * 16 + lr][ks * 32 + lk * 8]);
    size_t bidx = ((size_t)(w * 16 + ks) * 64 + lane) * 8;
    bf16x8 Bh = *reinterpret_cast<const bf16x8*>(&w2h[bidx]);
    bf16x8 Bl = *reinterpret_cast<const bf16x8*>(&w2l[bidx]);
    #pragma unroll
    for (int rf = 0; rf < 2; ++rf) {
      accB[rf] = __builtin_amdgcn_mfma_f32_16x16x32_bf16(Ah[rf], Bh, accB[rf], 0, 0, 0);
      accB[rf] = __builtin_amdgcn_mfma_f32_16x16x32_bf16(Ah[rf], Bl, accB[rf], 0, 0, 0);
    }
  }
  int hh2 = lr >> 3, jj = lr & 7;
  int headB = 2 * w + hh2;
  float aS = a2[headB * 16 + jj];
  float aD = a2[headB * 16 + 8 + jj];
  #pragma unroll
  for (int rf = 0; rf < 2; ++rf) {
    #pragma unroll
    for (int r = 0; r < 4; ++r) {
      int row = row0 + rf * 16 + lk * 4 + r;
      float val = accB[rf][r];
      if (row < N)
        h2p[(size_t)row * 64 + w * 16 + lr] = (u16)cvt_pk_bf16(val, val);
      float ps = val * aS, pd = val * aD;
      ps += __shfl_xor(ps, 1); ps += __shfl_xor(ps, 2); ps += __shfl_xor(ps, 4);
      pd += __shfl_xor(pd, 1); pd += __shfl_xor(pd, 2); pd += __shfl_xor(pd, 4);
      if (jj == 0 && row < N) {
        ss2[(size_t)row * 8 + headB] = ps;
        sd2[(size_t)row * 8 + headB] = pd;
      }
    }
  }
}

// Layer-2 aggregation: one wave per node; lane = (li = lane>>3, fg = lane&7).
// 16 edge slots per iteration (2 per lane), 2-deep pipelined prefetch.
__global__ __launch_bounds__(256) void k_agg2(const u16* __restrict__ H,
        const float* __restrict__ ss, const float* __restrict__ sd,
        const int* __restrict__ offs, const int* __restrict__ adj,
        float* __restrict__ outp, int n) {
  int node = (blockIdx.x * 256 + threadIdx.x) >> 6;
  int lane = threadIdx.x & 63;
  if (node >= n) return;
  int li = lane >> 3, fg = lane & 7;
  int beg = offs[node], end = offs[node + 1];
  float sS = ss[node * 8 + fg];
  f32x2 acc2[4] = {};
  float rsum = 0.f;

  auto adj2 = [&](int e, int slot) -> u32 {
    int mm = end - e; if (mm > 16) mm = 16;
    int ii = slot < mm ? slot : mm - 1;
    return (u32)adj[e + ii];
  };

  u32 d0n = 0, d1n = 0;
  if (beg + 16 < end) { d0n = adj2(beg + 16, li); d1n = adj2(beg + 16, li + 8); }
  u32 d0 = adj2(beg, li), d1 = adj2(beg, li + 8);
  uint4 rv0 = ld16(H, d0 * 128u + fg * 16u);
  uint4 rv1 = ld16(H, d1 * 128u + fg * 16u);
  float sd0 = sd[d0 * 8u + fg], sd1 = sd[d1 * 8u + fg];

  for (int e = beg; e < end; e += 16) {
    u32 d0nn = 0, d1nn = 0;
    if (e + 32 < end) { d0nn = adj2(e + 32, li); d1nn = adj2(e + 32, li + 8); }
    int mc = end - e; if (mc > 16) mc = 16;
    float z0 = sS + sd0, z1 = sS + sd1;
    float w0 = __expf(-(z0 > 0.f ? z0 : 0.2f * z0));
    float w1 = __expf(-(z1 > 0.f ? z1 : 0.2f * z1));
    w0 = li < mc ? w0 : 0.f;
    w1 = (li + 8) < mc ? w1 : 0.f;
    rsum += w0 + w1;
    bool hn = (e + 16) < end;
    uint4 rv0N = {}, rv1N = {};
    float sd0N = 0.f, sd1N = 0.f;
    if (hn) {
      rv0N = ld16(H, d0n * 128u + fg * 16u);
      rv1N = ld16(H, d1n * 128u + fg * 16u);
      sd0N = sd[d0n * 8u + fg];
      sd1N = sd[d1n * 8u + fg];
    }
    f32x2 W0 = {w0, w0}, W1v = {w1, w1};
    acc2[0] += W0 * up2(rv0.x);
    acc2[1] += W0 * up2(rv0.y);
    acc2[2] += W0 * up2(rv0.z);
    acc2[3] += W0 * up2(rv0.w);
    acc2[0] += W1v * up2(rv1.x);
    acc2[1] += W1v * up2(rv1.y);
    acc2[2] += W1v * up2(rv1.z);
    acc2[3] += W1v * up2(rv1.w);
    if (hn) { rv0 = rv0N; rv1 = rv1N; sd0 = sd0N; sd1 = sd1N; }
    d0n = d0nn; d1n = d1nn;
  }
  #pragma unroll
  for (int mask = 8; mask < 64; mask <<= 1) {
    rsum += __shfl_xor(rsum, mask);
    #pragma unroll
    for (int k = 0; k < 4; k++) {
      acc2[k].x += __shfl_xor(acc2[k].x, mask);
      acc2[k].y += __shfl_xor(acc2[k].y, mask);
    }
  }
  if (li == 0) {
    float inv = 1.f / rsum;
    float o[8];
    #pragma unroll
    for (int k = 0; k < 4; k++) {
      float v0 = acc2[k].x * inv, v1 = acc2[k].y * inv;
      o[2 * k]     = v0 > 0.f ? v0 : expm1f(v0);
      o[2 * k + 1] = v1 > 0.f ? v1 : expm1f(v1);
    }
    float4* Ov = reinterpret_cast<float4*>(outp);
    Ov[(size_t)node * 16 + fg * 2]     = make_float4(o[0], o[1], o[2], o[3]);
    Ov[(size_t)node * 16 + fg * 2 + 1] = make_float4(o[4], o[5], o[6], o[7]);
  }
}

extern "C" void kernel_launch(void* const* d_in, const int* in_sizes, int n_in,
                              void* d_out, int out_size, void* d_ws, size_t ws_size,
                              hipStream_t stream) {
  const float* x  = (const float*)d_in[0];
  const int*   ei = (const int*)d_in[1];
  const float* W1 = (const float*)d_in[2];
  const float* a1 = (const float*)d_in[3];
  const float* W2 = (const float*)d_in[4];
  const float* a2 = (const float*)d_in[5];
  float* out = (float*)d_out;

  int N = in_sizes[0] / TNFEAT;   // 50000
  int E = in_sizes[1] / 2;        // 850000
  const int* src = ei;
  const int* dst = ei + E;
  int NB = (N + 1023) / 1024;

  char* base = (char*)d_ws;
  size_t off = 0;
  auto take = [&](size_t bytes) { char* p = base + off; off = (off + bytes + 255) & ~(size_t)255; return p; };
  u16*   xb    = (u16*)take((size_t)N * TNFEAT * 2);       // 12.8 MB
  u16*   g     = (u16*)take((size_t)N * 8 * TNFEAT * 2);   // 102.4 MB
  u16*   h2p   = (u16*)take((size_t)N * C2 * 2);           // 6.4 MB
  u16*   w1hi  = (u16*)take(65536 * 2);
  u16*   w1lo  = (u16*)take(65536 * 2);
  u16*   w2hi  = (u16*)take(32768 * 2);
  u16*   w2lo  = (u16*)take(32768 * 2);
  u16*   vhi   = (u16*)take(2048 * 2);
  u16*   vlo   = (u16*)take(2048 * 2);
  float* s1s   = (float*)take((size_t)N * 8 * 4);
  float* s1d   = (float*)take((size_t)N * 8 * 4);
  float* s2s   = (float*)take((size_t)N * 8 * 4);
  float* s2d   = (float*)take((size_t)N * 8 * 4);
  float* rs    = (float*)take((size_t)N * 8 * 4);
  int*   deg   = (int*)take((size_t)N * 4);
  int*   offs  = (int*)take((size_t)(N + 1) * 4);
  int*   cur   = (int*)take((size_t)N * 4);
  int*   loc   = (int*)take((size_t)N * 4);
  int*   bsum  = (int*)take(64 * 4);
  int*   adj   = (int*)take((size_t)E * 4);

  // CSR build (by src)
  hipLaunchKernelGGL(k_zero, dim3((N + 255) / 256), dim3(256), 0, stream, deg, N);
  hipLaunchKernelGGL(k_hist, dim3((E + 255) / 256), dim3(256), 0, stream, src, deg, E);
  hipLaunchKernelGGL(k_bscan1, dim3(NB), dim3(1024), 0, stream, deg, loc, bsum, N);
  hipLaunchKernelGGL(k_bscan2, dim3(1), dim3(64), 0, stream, bsum, NB);
  hipLaunchKernelGGL(k_offs, dim3(NB), dim3(1024), 0, stream, loc, bsum, deg, offs, cur, N);
  hipLaunchKernelGGL(k_fill, dim3((E + 255) / 256), dim3(256), 0, stream, src, dst, cur, adj, E);

  // Weight packing + score-projection vectors (single launch)
  hipLaunchKernelGGL(k_packAll, dim3(392), dim3(256), 0, stream,
                     W1, W2, a1, w1hi, w1lo, w2hi, w2lo, vhi, vlo);

  // Layer 1: xb + scores, x-space aggregation
  hipLaunchKernelGGL(k_xprep, dim3((N + 63) / 64), dim3(256), 0, stream,
                     x, vhi, vlo, xb, s1s, s1d, N);
  hipLaunchKernelGGL(k_agg1x, dim3((N + 3) / 4), dim3(256), 0, stream,
                     xb, s1s, s1d, offs, adj, g, rs, N);

  // Fused: per-head GEMM1-apply + GEMM2 + layer-2 scores
  hipLaunchKernelGGL(k_gemm12, dim3((N + 31) / 32), dim3(256), 0, stream,
                     g, w1hi, w1lo, rs, w2hi, w2lo, a2, h2p, s2s, s2d, N);

  // Layer 2 aggregation
  hipLaunchKernelGGL(k_agg2, dim3((N + 3) / 4), dim3(256), 0, stream,
                     h2p, s2s, s2d, offs, adj, out, N);
}

// Round 12
// 245.763 us; speedup vs baseline: 1.4976x; 1.0636x over previous
//
#include <hip/hip_runtime.h>
#include <math.h>

typedef unsigned int u32;
typedef unsigned short u16;
typedef __attribute__((ext_vector_type(8))) short bf16x8;
typedef __attribute__((ext_vector_type(4))) float f32x4;
typedef __attribute__((ext_vector_type(2))) float f32x2;

static constexpr int TNFEAT  = 128;
static constexpr int TNHEADS = 8;
static constexpr int C1      = 512;  // NHID*NHEADS
static constexpr int C2      = 64;   // NCLASS

__device__ inline float bf2f(u16 u) {
  union { u32 i; float f; } c; c.i = ((u32)u) << 16; return c.f;
}
__device__ inline float bitsf(u32 u) {
  union { u32 i; float f; } c; c.i = u; return c.f;
}
__device__ inline u16 f2bf(float f) {
  union { float f; u32 i; } c; c.f = f;
  u32 r = c.i + 0x7FFF + ((c.i >> 16) & 1);   // round-nearest-even
  return (u16)(r >> 16);
}
__device__ inline u32 cvt_pk_bf16(float lo, float hi) {
  u32 r;
  asm volatile("v_cvt_pk_bf16_f32 %0, %1, %2" : "=v"(r) : "v"(lo), "v"(hi));
  return r;
}
__device__ inline uint4 ld16(const u16* base, u32 byteoff) {
  return *reinterpret_cast<const uint4*>(reinterpret_cast<const char*>(base) + byteoff);
}
__device__ inline f32x2 up2(u32 q) {
  f32x2 p;
  p.x = bitsf(q << 16);
  p.y = bitsf(q & 0xffff0000u);
  return p;
}
// fast elu for v<=0 region handled branchlessly; abs err ~1e-7, fine vs 1e-2 budget
__device__ inline float elu_fast(float v) {
  return v > 0.f ? v : (__expf(v) - 1.f);
}
// wave-uniform broadcast from compile-time lane via readlane (VALU/SGPR, no LDS pipe)
__device__ inline int rdl_i(int v, int l) { return __builtin_amdgcn_readlane(v, l); }
__device__ inline float rdl_f(float v, int l) {
  union { float f; int i; } c; c.f = v;
  union { int i; float f; } d; d.i = __builtin_amdgcn_readlane(c.i, l);
  return d.f;
}

__global__ void k_zero(int* __restrict__ p, int n) {
  int i = blockIdx.x * blockDim.x + threadIdx.x;
  if (i < n) p[i] = 0;
}

__global__ void k_hist(const int* __restrict__ src, int* __restrict__ deg, int E) {
  int i = blockIdx.x * blockDim.x + threadIdx.x;
  if (i < E) atomicAdd(&deg[src[i]], 1);
}

__global__ __launch_bounds__(1024) void k_bscan1(const int* __restrict__ deg,
                                                 int* __restrict__ loc,
                                                 int* __restrict__ bsum, int n) {
  __shared__ int sdata[1024];
  int t = threadIdx.x;
  int i = blockIdx.x * 1024 + t;
  int v = (i < n) ? deg[i] : 0;
  sdata[t] = v;
  __syncthreads();
  for (int ofs = 1; ofs < 1024; ofs <<= 1) {
    int tv = (t >= ofs) ? sdata[t - ofs] : 0;
    __syncthreads();
    sdata[t] += tv;
    __syncthreads();
  }
  if (i < n) loc[i] = sdata[t];
  if (t == 1023) bsum[blockIdx.x] = sdata[1023];
}

__global__ void k_bscan2(int* __restrict__ bsum, int nb) {
  int t = threadIdx.x;
  int v = (t < nb) ? bsum[t] : 0;
  #pragma unroll
  for (int ofs = 1; ofs < 64; ofs <<= 1) {
    int u = __shfl_up(v, ofs);
    if (t >= ofs) v += u;
  }
  if (t < nb) bsum[t] = v;
}

__global__ __launch_bounds__(1024) void k_offs(const int* __restrict__ loc,
                                               const int* __restrict__ bsum,
                                               const int* __restrict__ deg,
                                               int* __restrict__ offs,
                                               int* __restrict__ cur, int n) {
  int b = blockIdx.x;
  int i = b * 1024 + threadIdx.x;
  int base = (b > 0) ? bsum[b - 1] : 0;
  if (i < n) {
    int v = base + loc[i];
    offs[i + 1] = v;
    cur[i] = v - deg[i];
  }
  if (i == 0) offs[0] = 0;
}

__global__ void k_fill(const int* __restrict__ src, const int* __restrict__ dst,
                       int* __restrict__ cur, int* __restrict__ adj, int E) {
  int i = blockIdx.x * blockDim.x + threadIdx.x;
  if (i < E) {
    int p = atomicAdd(&cur[src[i]], 1);
    adj[p] = dst[i];
  }
}

// One launch: blocks [0,256) pack W1, [256,384) pack W2, [384,392) pack Vsd.
__global__ void k_packAll(const float* __restrict__ W1, const float* __restrict__ W2,
                          const float* __restrict__ a1,
                          u16* __restrict__ w1hi, u16* __restrict__ w1lo,
                          u16* __restrict__ w2hi, u16* __restrict__ w2lo,
                          u16* __restrict__ vhi, u16* __restrict__ vlo) {
  int b = blockIdx.x;
  if (b < 256) {
    int idx = b * 256 + threadIdx.x;   // 65536
    int j = idx & 7, lane = (idx >> 3) & 63, ks = (idx >> 9) & 3, cg = idx >> 11;
    int col = cg * 16 + (lane & 15);
    int k = ks * 32 + (lane >> 4) * 8 + j;
    float f = W1[((size_t)(col >> 6) * 128 + k) * 64 + (col & 63)];
    u16 h = f2bf(f);
    w1hi[idx] = h;
    w1lo[idx] = f2bf(f - bf2f(h));
  } else if (b < 384) {
    int idx = (b - 256) * 256 + threadIdx.x;   // 32768
    int j = idx & 7, lane = (idx >> 3) & 63, ks = (idx >> 9) & 15, cg = idx >> 13;
    int col = cg * 16 + (lane & 15);
    int k = ks * 32 + (lane >> 4) * 8 + j;
    float f = W2[((size_t)(col >> 3) * 512 + k) * 8 + (col & 7)];
    u16 h = f2bf(f);
    w2hi[idx] = h;
    w2lo[idx] = f2bf(f - bf2f(h));
  } else {
    int idx = (b - 384) * 256 + threadIdx.x;   // 2048
    int j = idx & 7, lane = (idx >> 3) & 63, ks = idx >> 9;
    int k = ks * 32 + (lane >> 4) * 8 + j;
    int c = lane & 15;
    int h = c >> 1, s = c & 1;
    const float* wrow = W1 + ((size_t)h * 128 + k) * 64;
    const float* av = a1 + h * 128 + s * 64;
    float dot = 0.f;
    #pragma unroll 8
    for (int f = 0; f < 64; f++) dot = fmaf(wrow[f], av[f], dot);
    u16 hb = f2bf(dot);
    vhi[idx] = hb;
    vlo[idx] = f2bf(dot - bf2f(hb));
  }
}

// x [N,128] fp32 -> xb bf16 [N,128]; scores [N,16] = x @ Vsd -> s1s/s1d (3-term MFMA)
__global__ __launch_bounds__(256) void k_xprep(const float* __restrict__ x,
        const u16* __restrict__ vhi, const u16* __restrict__ vlo,
        u16* __restrict__ xb, float* __restrict__ ss, float* __restrict__ sd, int N) {
  int w = threadIdx.x >> 6, lane = threadIdx.x & 63;
  int lr = lane & 15, lk = lane >> 4;
  int row0 = blockIdx.x * 64 + w * 16;
  f32x4 acc = {0.f, 0.f, 0.f, 0.f};
  for (int ks = 0; ks < 4; ++ks) {
    int row = row0 + lr;
    int rc = row < N ? row : 0;
    const float* ap = x + (size_t)rc * 128 + ks * 32 + lk * 8;
    float4 f0 = *reinterpret_cast<const float4*>(ap);
    float4 f1 = *reinterpret_cast<const float4*>(ap + 4);
    float fa[8] = {f0.x, f0.y, f0.z, f0.w, f1.x, f1.y, f1.z, f1.w};
    union { u32 u[4]; bf16x8 v; uint4 q; } ch, cl;
    #pragma unroll
    for (int p = 0; p < 4; ++p) {
      float e0 = fa[2 * p], e1 = fa[2 * p + 1];
      u32 h = cvt_pk_bf16(e0, e1);
      ch.u[p] = h;
      cl.u[p] = cvt_pk_bf16(e0 - bitsf(h << 16), e1 - bitsf(h & 0xffff0000u));
    }
    if (row < N)
      *reinterpret_cast<uint4*>(&xb[(size_t)row * 128 + ks * 32 + lk * 8]) = ch.q;
    size_t bidx = ((size_t)ks * 64 + lane) * 8;
    bf16x8 Bh = *reinterpret_cast<const bf16x8*>(&vhi[bidx]);
    bf16x8 Bl = *reinterpret_cast<const bf16x8*>(&vlo[bidx]);
    acc = __builtin_amdgcn_mfma_f32_16x16x32_bf16(ch.v, Bh, acc, 0, 0, 0);
    acc = __builtin_amdgcn_mfma_f32_16x16x32_bf16(cl.v, Bh, acc, 0, 0, 0);
    acc = __builtin_amdgcn_mfma_f32_16x16x32_bf16(ch.v, Bl, acc, 0, 0, 0);
  }
  int h = lr >> 1, s = lr & 1;
  float* dstp = (s == 0) ? ss : sd;
  #pragma unroll
  for (int r = 0; r < 4; ++r) {
    int row = row0 + lk * 4 + r;
    if (row < N) dstp[row * 8 + h] = acc[r];
  }
}

// Layer-1 x-aggregation (r7 structure + readlane broadcasts).
// NEW: rsum is folded into the g write (g = weighted-x-sum / rsum), so the
// downstream GEMM needs no per-row divide and the rs buffer is gone.
__global__ __launch_bounds__(256) void k_agg1x(const u16* __restrict__ xb,
        const float* __restrict__ ss, const float* __restrict__ sd,
        const int* __restrict__ offs, const int* __restrict__ adj,
        u16* __restrict__ g, int n) {
  int node = (blockIdx.x * 256 + threadIdx.x) >> 6;
  int lane = threadIdx.x & 63;
  if (node >= n) return;
  int head = lane >> 3, li = lane & 7;
  int beg = offs[node], end = offs[node + 1];
  float sS = ss[node * 8 + head];
  const char* xbb = reinterpret_cast<const char*>(xb);
  f32x2 acc2[8] = {};
  float rsum = 0.f;
  int e = beg;
  for (; e + 8 <= end; e += 8) {
    int dl = adj[e + li];
    float z = sS + sd[(u32)dl * 8u + head];
    float w = __expf(-(z > 0.f ? z : 0.2f * z));
    rsum += w;
    u32 qv[8];
    #pragma unroll
    for (int i = 0; i < 8; i++) {
      u32 di = (u32)rdl_i(dl, i);                  // SGPR dst index
      qv[i] = *reinterpret_cast<const u32*>(xbb + di * 256u + lane * 4u);
    }
    #pragma unroll
    for (int i = 0; i < 8; i++) {
      f32x2 xv = up2(qv[i]);
      #pragma unroll
      for (int h2 = 0; h2 < 8; h2++) {
        float wi = rdl_f(w, h2 * 8 + i);           // SGPR weight
        acc2[h2] += (f32x2){wi, wi} * xv;
      }
    }
  }
  if (e < end) {
    int m = end - e;
    int lic = li < m ? li : m - 1;
    int dl = adj[e + lic];
    float z = sS + sd[(u32)dl * 8u + head];
    float w = __expf(-(z > 0.f ? z : 0.2f * z));
    if (li >= m) w = 0.f;
    rsum += w;
    u32 qv[8];
    #pragma unroll
    for (int i = 0; i < 8; i++) {
      if (i < m) {
        u32 di = (u32)rdl_i(dl, i);
        qv[i] = *reinterpret_cast<const u32*>(xbb + di * 256u + lane * 4u);
      }
    }
    #pragma unroll
    for (int i = 0; i < 8; i++) {
      if (i < m) {
        f32x2 xv = up2(qv[i]);
        #pragma unroll
        for (int h2 = 0; h2 < 8; h2++) {
          float wi = rdl_f(w, h2 * 8 + i);
          acc2[h2] += (f32x2){wi, wi} * xv;
        }
      }
    }
  }
  // reduce rsum over li within the head group, invert, broadcast all heads' inv
  rsum += __shfl_xor(rsum, 1);
  rsum += __shfl_xor(rsum, 2);
  rsum += __shfl_xor(rsum, 4);
  float inv = 1.f / rsum;                          // own head's inverse
  u32* gu = reinterpret_cast<u32*>(g);
  #pragma unroll
  for (int h2 = 0; h2 < 8; h2++) {
    float ih = rdl_f(inv, h2 * 8);                 // head h2's inverse (SGPR)
    gu[((size_t)node * 8 + h2) * 64 + lane] = cvt_pk_bf16(acc2[h2].x * ih, acc2[h2].y * ih);
  }
}

// Fused GEMM1-apply + GEMM2 + scores: block = 32 rows.
// Phase A: wave w computes heads 2w,2w+1 -> elu(g@W1) -> LDS h1 tile (bf16).
// Phase B: wave w computes output cols w*16..+16 of GEMM2 + fused scores.
__global__ __launch_bounds__(256) void k_gemm12(const u16* __restrict__ g,
        const u16* __restrict__ w1h, const u16* __restrict__ w1l,
        const u16* __restrict__ w2h, const u16* __restrict__ w2l,
        const float* __restrict__ a2,
        u16* __restrict__ h2p, float* __restrict__ ss2, float* __restrict__ sd2,
        int N) {
  __shared__ u16 h1t[32][516];   // 516 = 512 + 4 pad (2-way-free LDS banks)
  int w = threadIdx.x >> 6, lane = threadIdx.x & 63;
  int lr = lane & 15, lk = lane >> 4;
  int row0 = blockIdx.x * 32;
  // ---- Phase A ----
  for (int hh = 0; hh < 2; ++hh) {
    int head = 2 * w + hh;
    f32x4 acc[2][4] = {};
    for (int ks = 0; ks < 4; ++ks) {
      bf16x8 Ah[2];
      #pragma unroll
      for (int rf = 0; rf < 2; ++rf) {
        int row = row0 + rf * 16 + lr;
        int rc = row < N ? row : 0;
        Ah[rf] = *reinterpret_cast<const bf16x8*>(
            &g[((size_t)rc * 8 + head) * 128 + ks * 32 + lk * 8]);
      }
      #pragma unroll
      for (int cf = 0; cf < 4; ++cf) {
        size_t bidx = ((size_t)((head * 4 + cf) * 4 + ks) * 64 + lane) * 8;
        bf16x8 Bh = *reinterpret_cast<const bf16x8*>(&w1h[bidx]);
        bf16x8 Bl = *reinterpret_cast<const bf16x8*>(&w1l[bidx]);
        #pragma unroll
        for (int rf = 0; rf < 2; ++rf) {
          acc[rf][cf] = __builtin_amdgcn_mfma_f32_16x16x32_bf16(Ah[rf], Bh, acc[rf][cf], 0, 0, 0);
          acc[rf][cf] = __builtin_amdgcn_mfma_f32_16x16x32_bf16(Ah[rf], Bl, acc[rf][cf], 0, 0, 0);
        }
      }
    }
    #pragma unroll
    for (int rf = 0; rf < 2; ++rf) {
      #pragma unroll
      for (int r = 0; r < 4; ++r) {
        int srow = rf * 16 + lk * 4 + r;
        #pragma unroll
        for (int cf = 0; cf < 4; ++cf) {
          float v = elu_fast(acc[rf][cf][r]);
          h1t[srow][head * 64 + cf * 16 + lr] = (u16)cvt_pk_bf16(v, v);
        }
      }
    }
  }
  __syncthreads();
  // ---- Phase B ----
  f32x4 accB[2] = {};
  for (int ks = 0; ks < 16; ++ks) {
    bf16x8 Ah[2];
    #pragma unroll
    for (int rf = 0; rf < 2; ++rf)
      Ah[rf] = *reinterpret_cast<const bf16x8*>(&h1t[rf * 16 + lr][ks * 32 + lk * 8]);
    size_t bidx = ((size_t)(w * 16 + ks) * 64 + lane) * 8;
    bf16x8 Bh = *reinterpret_cast<const bf16x8*>(&w2h[bidx]);
    bf16x8 Bl = *reinterpret_cast<const bf16x8*>(&w2l[bidx]);
    #pragma unroll
    for (int rf = 0; rf < 2; ++rf) {
      accB[rf] = __builtin_amdgcn_mfma_f32_16x16x32_bf16(Ah[rf], Bh, accB[rf], 0, 0, 0);
      accB[rf] = __builtin_amdgcn_mfma_f32_16x16x32_bf16(Ah[rf], Bl, accB[rf], 0, 0, 0);
    }
  }
  int hh2 = lr >> 3, jj = lr & 7;
  int headB = 2 * w + hh2;
  float aS = a2[headB * 16 + jj];
  float aD = a2[headB * 16 + 8 + jj];
  #pragma unroll
  for (int rf = 0; rf < 2; ++rf) {
    #pragma unroll
    for (int r = 0; r < 4; ++r) {
      int row = row0 + rf * 16 + lk * 4 + r;
      float val = accB[rf][r];
      if (row < N)
        h2p[(size_t)row * 64 + w * 16 + lr] = (u16)cvt_pk_bf16(val, val);
      float ps = val * aS, pd = val * aD;
      ps += __shfl_xor(ps, 1); ps += __shfl_xor(ps, 2); ps += __shfl_xor(ps, 4);
      pd += __shfl_xor(pd, 1); pd += __shfl_xor(pd, 2); pd += __shfl_xor(pd, 4);
      if (jj == 0 && row < N) {
        ss2[(size_t)row * 8 + headB] = ps;
        sd2[(size_t)row * 8 + headB] = pd;
      }
    }
  }
}

// Layer-2 aggregation: one wave per node; lane = (li = lane>>3, fg = lane&7).
// 16 edge slots per iteration (2 per lane), 2-deep pipelined prefetch.
__global__ __launch_bounds__(256) void k_agg2(const u16* __restrict__ H,
        const float* __restrict__ ss, const float* __restrict__ sd,
        const int* __restrict__ offs, const int* __restrict__ adj,
        float* __restrict__ outp, int n) {
  int node = (blockIdx.x * 256 + threadIdx.x) >> 6;
  int lane = threadIdx.x & 63;
  if (node >= n) return;
  int li = lane >> 3, fg = lane & 7;
  int beg = offs[node], end = offs[node + 1];
  float sS = ss[node * 8 + fg];
  f32x2 acc2[4] = {};
  float rsum = 0.f;

  auto adj2 = [&](int e, int slot) -> u32 {
    int mm = end - e; if (mm > 16) mm = 16;
    int ii = slot < mm ? slot : mm - 1;
    return (u32)adj[e + ii];
  };

  u32 d0n = 0, d1n = 0;
  if (beg + 16 < end) { d0n = adj2(beg + 16, li); d1n = adj2(beg + 16, li + 8); }
  u32 d0 = adj2(beg, li), d1 = adj2(beg, li + 8);
  uint4 rv0 = ld16(H, d0 * 128u + fg * 16u);
  uint4 rv1 = ld16(H, d1 * 128u + fg * 16u);
  float sd0 = sd[d0 * 8u + fg], sd1 = sd[d1 * 8u + fg];

  for (int e = beg; e < end; e += 16) {
    u32 d0nn = 0, d1nn = 0;
    if (e + 32 < end) { d0nn = adj2(e + 32, li); d1nn = adj2(e + 32, li + 8); }
    int mc = end - e; if (mc > 16) mc = 16;
    float z0 = sS + sd0, z1 = sS + sd1;
    float w0 = __expf(-(z0 > 0.f ? z0 : 0.2f * z0));
    float w1 = __expf(-(z1 > 0.f ? z1 : 0.2f * z1));
    w0 = li < mc ? w0 : 0.f;
    w1 = (li + 8) < mc ? w1 : 0.f;
    rsum += w0 + w1;
    bool hn = (e + 16) < end;
    uint4 rv0N = {}, rv1N = {};
    float sd0N = 0.f, sd1N = 0.f;
    if (hn) {
      rv0N = ld16(H, d0n * 128u + fg * 16u);
      rv1N = ld16(H, d1n * 128u + fg * 16u);
      sd0N = sd[d0n * 8u + fg];
      sd1N = sd[d1n * 8u + fg];
    }
    f32x2 W0 = {w0, w0}, W1v = {w1, w1};
    acc2[0] += W0 * up2(rv0.x);
    acc2[1] += W0 * up2(rv0.y);
    acc2[2] += W0 * up2(rv0.z);
    acc2[3] += W0 * up2(rv0.w);
    acc2[0] += W1v * up2(rv1.x);
    acc2[1] += W1v * up2(rv1.y);
    acc2[2] += W1v * up2(rv1.z);
    acc2[3] += W1v * up2(rv1.w);
    if (hn) { rv0 = rv0N; rv1 = rv1N; sd0 = sd0N; sd1 = sd1N; }
    d0n = d0nn; d1n = d1nn;
  }
  #pragma unroll
  for (int mask = 8; mask < 64; mask <<= 1) {
    rsum += __shfl_xor(rsum, mask);
    #pragma unroll
    for (int k = 0; k < 4; k++) {
      acc2[k].x += __shfl_xor(acc2[k].x, mask);
      acc2[k].y += __shfl_xor(acc2[k].y, mask);
    }
  }
  if (li == 0) {
    float inv = 1.f / rsum;
    float o[8];
    #pragma unroll
    for (int k = 0; k < 4; k++) {
      o[2 * k]     = elu_fast(acc2[k].x * inv);
      o[2 * k + 1] = elu_fast(acc2[k].y * inv);
    }
    float4* Ov = reinterpret_cast<float4*>(outp);
    Ov[(size_t)node * 16 + fg * 2]     = make_float4(o[0], o[1], o[2], o[3]);
    Ov[(size_t)node * 16 + fg * 2 + 1] = make_float4(o[4], o[5], o[6], o[7]);
  }
}

extern "C" void kernel_launch(void* const* d_in, const int* in_sizes, int n_in,
                              void* d_out, int out_size, void* d_ws, size_t ws_size,
                              hipStream_t stream) {
  const float* x  = (const float*)d_in[0];
  const int*   ei = (const int*)d_in[1];
  const float* W1 = (const float*)d_in[2];
  const float* a1 = (const float*)d_in[3];
  const float* W2 = (const float*)d_in[4];
  const float* a2 = (const float*)d_in[5];
  float* out = (float*)d_out;

  int N = in_sizes[0] / TNFEAT;   // 50000
  int E = in_sizes[1] / 2;        // 850000
  const int* src = ei;
  const int* dst = ei + E;
  int NB = (N + 1023) / 1024;

  char* base = (char*)d_ws;
  size_t off = 0;
  auto take = [&](size_t bytes) { char* p = base + off; off = (off + bytes + 255) & ~(size_t)255; return p; };
  u16*   xb    = (u16*)take((size_t)N * TNFEAT * 2);       // 12.8 MB
  u16*   g     = (u16*)take((size_t)N * 8 * TNFEAT * 2);   // 102.4 MB
  u16*   h2p   = (u16*)take((size_t)N * C2 * 2);           // 6.4 MB
  u16*   w1hi  = (u16*)take(65536 * 2);
  u16*   w1lo  = (u16*)take(65536 * 2);
  u16*   w2hi  = (u16*)take(32768 * 2);
  u16*   w2lo  = (u16*)take(32768 * 2);
  u16*   vhi   = (u16*)take(2048 * 2);
  u16*   vlo   = (u16*)take(2048 * 2);
  float* s1s   = (float*)take((size_t)N * 8 * 4);
  float* s1d   = (float*)take((size_t)N * 8 * 4);
  float* s2s   = (float*)take((size_t)N * 8 * 4);
  float* s2d   = (float*)take((size_t)N * 8 * 4);
  int*   deg   = (int*)take((size_t)N * 4);
  int*   offs  = (int*)take((size_t)(N + 1) * 4);
  int*   cur   = (int*)take((size_t)N * 4);
  int*   loc   = (int*)take((size_t)N * 4);
  int*   bsum  = (int*)take(64 * 4);
  int*   adj   = (int*)take((size_t)E * 4);

  // CSR build (by src)
  hipLaunchKernelGGL(k_zero, dim3((N + 255) / 256), dim3(256), 0, stream, deg, N);
  hipLaunchKernelGGL(k_hist, dim3((E + 255) / 256), dim3(256), 0, stream, src, deg, E);
  hipLaunchKernelGGL(k_bscan1, dim3(NB), dim3(1024), 0, stream, deg, loc, bsum, N);
  hipLaunchKernelGGL(k_bscan2, dim3(1), dim3(64), 0, stream, bsum, NB);
  hipLaunchKernelGGL(k_offs, dim3(NB), dim3(1024), 0, stream, loc, bsum, deg, offs, cur, N);
  hipLaunchKernelGGL(k_fill, dim3((E + 255) / 256), dim3(256), 0, stream, src, dst, cur, adj, E);

  // Weight packing + score-projection vectors (single launch)
  hipLaunchKernelGGL(k_packAll, dim3(392), dim3(256), 0, stream,
                     W1, W2, a1, w1hi, w1lo, w2hi, w2lo, vhi, vlo);

  // Layer 1: xb + scores, x-space aggregation (rsum-normalized g)
  hipLaunchKernelGGL(k_xprep, dim3((N + 63) / 64), dim3(256), 0, stream,
                     x, vhi, vlo, xb, s1s, s1d, N);
  hipLaunchKernelGGL(k_agg1x, dim3((N + 3) / 4), dim3(256), 0, stream,
                     xb, s1s, s1d, offs, adj, g, N);

  // Fused: per-head GEMM1-apply + GEMM2 + layer-2 scores
  hipLaunchKernelGGL(k_gemm12, dim3((N + 31) / 32), dim3(256), 0, stream,
                     g, w1hi, w1lo, w2hi, w2lo, a2, h2p, s2s, s2d, N);

  // Layer 2 aggregation
  hipLaunchKernelGGL(k_agg2, dim3((N + 3) / 4), dim3(256), 0, stream,
                     h2p, s2s, s2d, offs, adj, out, N);
}

// Round 13
// 225.457 us; speedup vs baseline: 1.6325x; 1.0901x over previous
//
#include <hip/hip_runtime.h>
#include <math.h>

typedef unsigned int u32;
typedef unsigned short u16;
typedef __attribute__((ext_vector_type(8))) short bf16x8;
typedef __attribute__((ext_vector_type(4))) float f32x4;
typedef __attribute__((ext_vector_type(2))) float f32x2;

static constexpr int TNFEAT  = 128;
static constexpr int TNHEADS = 8;
static constexpr int C1      = 512;  // NHID*NHEADS
static constexpr int C2      = 64;   // NCLASS

__device__ inline float bf2f(u16 u) {
  union { u32 i; float f; } c; c.i = ((u32)u) << 16; return c.f;
}
__device__ inline float bitsf(u32 u) {
  union { u32 i; float f; } c; c.i = u; return c.f;
}
__device__ inline u16 f2bf(float f) {
  union { float f; u32 i; } c; c.f = f;
  u32 r = c.i + 0x7FFF + ((c.i >> 16) & 1);   // round-nearest-even
  return (u16)(r >> 16);
}
__device__ inline u32 cvt_pk_bf16(float lo, float hi) {
  u32 r;
  asm volatile("v_cvt_pk_bf16_f32 %0, %1, %2" : "=v"(r) : "v"(lo), "v"(hi));
  return r;
}
__device__ inline uint4 ld16(const u16* base, u32 byteoff) {
  return *reinterpret_cast<const uint4*>(reinterpret_cast<const char*>(base) + byteoff);
}
__device__ inline f32x2 up2(u32 q) {
  f32x2 p;
  p.x = bitsf(q << 16);
  p.y = bitsf(q & 0xffff0000u);
  return p;
}
// fast elu: abs err ~1e-7 vs 1e-2 budget
__device__ inline float elu_fast(float v) {
  return v > 0.f ? v : (__expf(v) - 1.f);
}
// wave-uniform broadcast from compile-time lane via readlane
__device__ inline int rdl_i(int v, int l) { return __builtin_amdgcn_readlane(v, l); }
__device__ inline float rdl_f(float v, int l) {
  union { float f; int i; } c; c.f = v;
  union { int i; float f; } d; d.i = __builtin_amdgcn_readlane(c.i, l);
  return d.f;
}

__global__ void k_zero(int* __restrict__ p, int n) {
  int i = blockIdx.x * blockDim.x + threadIdx.x;
  if (i < n) p[i] = 0;
}

__global__ void k_hist(const int* __restrict__ src, int* __restrict__ deg, int E) {
  int i = blockIdx.x * blockDim.x + threadIdx.x;
  if (i < E) atomicAdd(&deg[src[i]], 1);
}

__global__ __launch_bounds__(1024) void k_bscan1(const int* __restrict__ deg,
                                                 int* __restrict__ loc,
                                                 int* __restrict__ bsum, int n) {
  __shared__ int sdata[1024];
  int t = threadIdx.x;
  int i = blockIdx.x * 1024 + t;
  int v = (i < n) ? deg[i] : 0;
  sdata[t] = v;
  __syncthreads();
  for (int ofs = 1; ofs < 1024; ofs <<= 1) {
    int tv = (t >= ofs) ? sdata[t - ofs] : 0;
    __syncthreads();
    sdata[t] += tv;
    __syncthreads();
  }
  if (i < n) loc[i] = sdata[t];
  if (t == 1023) bsum[blockIdx.x] = sdata[1023];
}

__global__ void k_bscan2(int* __restrict__ bsum, int nb) {
  int t = threadIdx.x;
  int v = (t < nb) ? bsum[t] : 0;
  #pragma unroll
  for (int ofs = 1; ofs < 64; ofs <<= 1) {
    int u = __shfl_up(v, ofs);
    if (t >= ofs) v += u;
  }
  if (t < nb) bsum[t] = v;
}

__global__ __launch_bounds__(1024) void k_offs(const int* __restrict__ loc,
                                               const int* __restrict__ bsum,
                                               const int* __restrict__ deg,
                                               int* __restrict__ offs,
                                               int* __restrict__ cur, int n) {
  int b = blockIdx.x;
  int i = b * 1024 + threadIdx.x;
  int base = (b > 0) ? bsum[b - 1] : 0;
  if (i < n) {
    int v = base + loc[i];
    offs[i + 1] = v;
    cur[i] = v - deg[i];
  }
  if (i == 0) offs[0] = 0;
}

__global__ void k_fill(const int* __restrict__ src, const int* __restrict__ dst,
                       int* __restrict__ cur, int* __restrict__ adj, int E) {
  int i = blockIdx.x * blockDim.x + threadIdx.x;
  if (i < E) {
    int p = atomicAdd(&cur[src[i]], 1);
    adj[p] = dst[i];
  }
}

// One launch: blocks [0,256) pack W1, [256,384) pack W2, [384,392) pack Vsd.
__global__ void k_packAll(const float* __restrict__ W1, const float* __restrict__ W2,
                          const float* __restrict__ a1,
                          u16* __restrict__ w1hi, u16* __restrict__ w1lo,
                          u16* __restrict__ w2hi, u16* __restrict__ w2lo,
                          u16* __restrict__ vhi, u16* __restrict__ vlo) {
  int b = blockIdx.x;
  if (b < 256) {
    int idx = b * 256 + threadIdx.x;   // 65536
    int j = idx & 7, lane = (idx >> 3) & 63, ks = (idx >> 9) & 3, cg = idx >> 11;
    int col = cg * 16 + (lane & 15);
    int k = ks * 32 + (lane >> 4) * 8 + j;
    float f = W1[((size_t)(col >> 6) * 128 + k) * 64 + (col & 63)];
    u16 h = f2bf(f);
    w1hi[idx] = h;
    w1lo[idx] = f2bf(f - bf2f(h));
  } else if (b < 384) {
    int idx = (b - 256) * 256 + threadIdx.x;   // 32768
    int j = idx & 7, lane = (idx >> 3) & 63, ks = (idx >> 9) & 15, cg = idx >> 13;
    int col = cg * 16 + (lane & 15);
    int k = ks * 32 + (lane >> 4) * 8 + j;
    float f = W2[((size_t)(col >> 3) * 512 + k) * 8 + (col & 7)];
    u16 h = f2bf(f);
    w2hi[idx] = h;
    w2lo[idx] = f2bf(f - bf2f(h));
  } else {
    int idx = (b - 384) * 256 + threadIdx.x;   // 2048
    int j = idx & 7, lane = (idx >> 3) & 63, ks = idx >> 9;
    int k = ks * 32 + (lane >> 4) * 8 + j;
    int c = lane & 15;
    int h = c >> 1, s = c & 1;
    const float* wrow = W1 + ((size_t)h * 128 + k) * 64;
    const float* av = a1 + h * 128 + s * 64;
    float dot = 0.f;
    #pragma unroll 8
    for (int f = 0; f < 64; f++) dot = fmaf(wrow[f], av[f], dot);
    u16 hb = f2bf(dot);
    vhi[idx] = hb;
    vlo[idx] = f2bf(dot - bf2f(hb));
  }
}

// x [N,128] fp32 -> xb bf16 [N,128]; scores [N,16] = x @ Vsd -> s1s/s1d (3-term MFMA)
__global__ __launch_bounds__(256) void k_xprep(const float* __restrict__ x,
        const u16* __restrict__ vhi, const u16* __restrict__ vlo,
        u16* __restrict__ xb, float* __restrict__ ss, float* __restrict__ sd, int N) {
  int w = threadIdx.x >> 6, lane = threadIdx.x & 63;
  int lr = lane & 15, lk = lane >> 4;
  int row0 = blockIdx.x * 64 + w * 16;
  f32x4 acc = {0.f, 0.f, 0.f, 0.f};
  for (int ks = 0; ks < 4; ++ks) {
    int row = row0 + lr;
    int rc = row < N ? row : 0;
    const float* ap = x + (size_t)rc * 128 + ks * 32 + lk * 8;
    float4 f0 = *reinterpret_cast<const float4*>(ap);
    float4 f1 = *reinterpret_cast<const float4*>(ap + 4);
    float fa[8] = {f0.x, f0.y, f0.z, f0.w, f1.x, f1.y, f1.z, f1.w};
    union { u32 u[4]; bf16x8 v; uint4 q; } ch, cl;
    #pragma unroll
    for (int p = 0; p < 4; ++p) {
      float e0 = fa[2 * p], e1 = fa[2 * p + 1];
      u32 h = cvt_pk_bf16(e0, e1);
      ch.u[p] = h;
      cl.u[p] = cvt_pk_bf16(e0 - bitsf(h << 16), e1 - bitsf(h & 0xffff0000u));
    }
    if (row < N)
      *reinterpret_cast<uint4*>(&xb[(size_t)row * 128 + ks * 32 + lk * 8]) = ch.q;
    size_t bidx = ((size_t)ks * 64 + lane) * 8;
    bf16x8 Bh = *reinterpret_cast<const bf16x8*>(&vhi[bidx]);
    bf16x8 Bl = *reinterpret_cast<const bf16x8*>(&vlo[bidx]);
    acc = __builtin_amdgcn_mfma_f32_16x16x32_bf16(ch.v, Bh, acc, 0, 0, 0);
    acc = __builtin_amdgcn_mfma_f32_16x16x32_bf16(cl.v, Bh, acc, 0, 0, 0);
    acc = __builtin_amdgcn_mfma_f32_16x16x32_bf16(ch.v, Bl, acc, 0, 0, 0);
  }
  int h = lr >> 1, s = lr & 1;
  float* dstp = (s == 0) ? ss : sd;
  #pragma unroll
  for (int r = 0; r < 4; ++r) {
    int row = row0 + lk * 4 + r;
    if (row < N) dstp[row * 8 + h] = acc[r];
  }
}

// Fused layer-1 aggregation + GEMM1-apply + GEMM2 + layer-2 scores.
// Block = 16 nodes, 16 waves (1024 thr): wave wid aggregates node base+wid
// (full per-node parallelism, r12 inner loop) -> normalized g row in LDS.
// Phase A: wave wid -> head wid>>1, colfrag pair (wid&1)*2 of elu(g@W1) -> LDS h1.
// Phase B: waves 0-3 -> GEMM2 cols wid*16..+16 + fused scores.
__global__ __launch_bounds__(1024, 8) void k_l12(const u16* __restrict__ xb,
        const float* __restrict__ ss, const float* __restrict__ sd,
        const int* __restrict__ offs, const int* __restrict__ adj,
        const u16* __restrict__ w1h, const u16* __restrict__ w1l,
        const u16* __restrict__ w2h, const u16* __restrict__ w2l,
        const float* __restrict__ a2,
        u16* __restrict__ h2p, float* __restrict__ ss2, float* __restrict__ sd2,
        int N) {
  __shared__ u32 g_lds[16 * 516];   // 33 KB: per node 8 heads x 64 u32 (+4 pad)
  __shared__ u16 h1t[16][516];      // 16.5 KB
  int wid = threadIdx.x >> 6;
  int lane = threadIdx.x & 63;
  int nodebase = blockIdx.x * 16;

  // ---- Aggregation: one wave per node ----
  {
    int node = nodebase + wid;
    int head = lane >> 3, li = lane & 7;
    u32* gu = g_lds + wid * 516;
    if (node < N) {
      int beg = offs[node], end = offs[node + 1];
      float sS = ss[node * 8 + head];
      const char* xbb = reinterpret_cast<const char*>(xb);
      f32x2 acc2[8] = {};
      float rsum = 0.f;
      int e = beg;
      for (; e + 8 <= end; e += 8) {
        int dl = adj[e + li];
        float z = sS + sd[(u32)dl * 8u + head];
        float w = __expf(-(z > 0.f ? z : 0.2f * z));
        rsum += w;
        u32 qv[8];
        #pragma unroll
        for (int i = 0; i < 8; i++) {
          u32 di = (u32)rdl_i(dl, i);
          qv[i] = *reinterpret_cast<const u32*>(xbb + di * 256u + lane * 4u);
        }
        #pragma unroll
        for (int i = 0; i < 8; i++) {
          f32x2 xv = up2(qv[i]);
          #pragma unroll
          for (int h2 = 0; h2 < 8; h2++) {
            float wi = rdl_f(w, h2 * 8 + i);
            acc2[h2] += (f32x2){wi, wi} * xv;
          }
        }
      }
      if (e < end) {
        int m = end - e;
        int lic = li < m ? li : m - 1;
        int dl = adj[e + lic];
        float z = sS + sd[(u32)dl * 8u + head];
        float w = __expf(-(z > 0.f ? z : 0.2f * z));
        if (li >= m) w = 0.f;
        rsum += w;
        u32 qv[8];
        #pragma unroll
        for (int i = 0; i < 8; i++) {
          if (i < m) {
            u32 di = (u32)rdl_i(dl, i);
            qv[i] = *reinterpret_cast<const u32*>(xbb + di * 256u + lane * 4u);
          }
        }
        #pragma unroll
        for (int i = 0; i < 8; i++) {
          if (i < m) {
            f32x2 xv = up2(qv[i]);
            #pragma unroll
            for (int h2 = 0; h2 < 8; h2++) {
              float wi = rdl_f(w, h2 * 8 + i);
              acc2[h2] += (f32x2){wi, wi} * xv;
            }
          }
        }
      }
      rsum += __shfl_xor(rsum, 1);
      rsum += __shfl_xor(rsum, 2);
      rsum += __shfl_xor(rsum, 4);
      float inv = 1.f / rsum;
      #pragma unroll
      for (int h2 = 0; h2 < 8; h2++) {
        float ih = rdl_f(inv, h2 * 8);
        gu[h2 * 64 + lane] = cvt_pk_bf16(acc2[h2].x * ih, acc2[h2].y * ih);
      }
    } else {
      #pragma unroll
      for (int h2 = 0; h2 < 8; h2++) gu[h2 * 64 + lane] = 0;
    }
  }
  __syncthreads();

  // ---- Phase A: elu(g @ W1) -> h1 tile ----
  {
    int headA = wid >> 1;
    int cf0 = (wid & 1) * 2;
    int lr = lane & 15, lk = lane >> 4;
    f32x4 acc[2] = {};
    const char* gb = reinterpret_cast<const char*>(g_lds);
    for (int ks = 0; ks < 4; ++ks) {
      bf16x8 Ah = *reinterpret_cast<const bf16x8*>(
          gb + lr * 2064 + headA * 256 + ks * 64 + lk * 16);
      #pragma unroll
      for (int c = 0; c < 2; ++c) {
        int cf = cf0 + c;
        size_t bidx = ((size_t)((headA * 4 + cf) * 4 + ks) * 64 + lane) * 8;
        bf16x8 Bh = *reinterpret_cast<const bf16x8*>(&w1h[bidx]);
        bf16x8 Bl = *reinterpret_cast<const bf16x8*>(&w1l[bidx]);
        acc[c] = __builtin_amdgcn_mfma_f32_16x16x32_bf16(Ah, Bh, acc[c], 0, 0, 0);
        acc[c] = __builtin_amdgcn_mfma_f32_16x16x32_bf16(Ah, Bl, acc[c], 0, 0, 0);
      }
    }
    #pragma unroll
    for (int r = 0; r < 4; ++r) {
      int srow = lk * 4 + r;
      #pragma unroll
      for (int c = 0; c < 2; ++c) {
        float v = elu_fast(acc[c][r]);
        h1t[srow][headA * 64 + (cf0 + c) * 16 + lr] = (u16)cvt_pk_bf16(v, v);
      }
    }
  }
  __syncthreads();

  // ---- Phase B: GEMM2 + scores (waves 0-3) ----
  if (wid < 4) {
    int lr = lane & 15, lk = lane >> 4;
    f32x4 acc0 = {}, acc1 = {};
    for (int ks = 0; ks < 16; ks += 2) {
      bf16x8 A0 = *reinterpret_cast<const bf16x8*>(&h1t[lr][ks * 32 + lk * 8]);
      bf16x8 A1 = *reinterpret_cast<const bf16x8*>(&h1t[lr][(ks + 1) * 32 + lk * 8]);
      size_t b0 = ((size_t)(wid * 16 + ks) * 64 + lane) * 8;
      size_t b1 = ((size_t)(wid * 16 + ks + 1) * 64 + lane) * 8;
      bf16x8 Bh0 = *reinterpret_cast<const bf16x8*>(&w2h[b0]);
      bf16x8 Bl0 = *reinterpret_cast<const bf16x8*>(&w2l[b0]);
      bf16x8 Bh1 = *reinterpret_cast<const bf16x8*>(&w2h[b1]);
      bf16x8 Bl1 = *reinterpret_cast<const bf16x8*>(&w2l[b1]);
      acc0 = __builtin_amdgcn_mfma_f32_16x16x32_bf16(A0, Bh0, acc0, 0, 0, 0);
      acc1 = __builtin_amdgcn_mfma_f32_16x16x32_bf16(A1, Bh1, acc1, 0, 0, 0);
      acc0 = __builtin_amdgcn_mfma_f32_16x16x32_bf16(A0, Bl0, acc0, 0, 0, 0);
      acc1 = __builtin_amdgcn_mfma_f32_16x16x32_bf16(A1, Bl1, acc1, 0, 0, 0);
    }
    f32x4 accB = acc0 + acc1;
    int hh2 = lr >> 3, jj = lr & 7;
    int headB = 2 * wid + hh2;
    float aS = a2[headB * 16 + jj];
    float aD = a2[headB * 16 + 8 + jj];
    #pragma unroll
    for (int r = 0; r < 4; ++r) {
      int row = nodebase + lk * 4 + r;
      float val = accB[r];
      if (row < N)
        h2p[(size_t)row * 64 + wid * 16 + lr] = (u16)cvt_pk_bf16(val, val);
      float ps = val * aS, pd = val * aD;
      ps += __shfl_xor(ps, 1); ps += __shfl_xor(ps, 2); ps += __shfl_xor(ps, 4);
      pd += __shfl_xor(pd, 1); pd += __shfl_xor(pd, 2); pd += __shfl_xor(pd, 4);
      if (jj == 0 && row < N) {
        ss2[(size_t)row * 8 + headB] = ps;
        sd2[(size_t)row * 8 + headB] = pd;
      }
    }
  }
}

// Layer-2 aggregation: one wave per node; lane = (li = lane>>3, fg = lane&7).
// 16 edge slots per iteration (2 per lane), 2-deep pipelined prefetch.
__global__ __launch_bounds__(256) void k_agg2(const u16* __restrict__ H,
        const float* __restrict__ ss, const float* __restrict__ sd,
        const int* __restrict__ offs, const int* __restrict__ adj,
        float* __restrict__ outp, int n) {
  int node = (blockIdx.x * 256 + threadIdx.x) >> 6;
  int lane = threadIdx.x & 63;
  if (node >= n) return;
  int li = lane >> 3, fg = lane & 7;
  int beg = offs[node], end = offs[node + 1];
  float sS = ss[node * 8 + fg];
  f32x2 acc2[4] = {};
  float rsum = 0.f;

  auto adj2 = [&](int e, int slot) -> u32 {
    int mm = end - e; if (mm > 16) mm = 16;
    int ii = slot < mm ? slot : mm - 1;
    return (u32)adj[e + ii];
  };

  u32 d0n = 0, d1n = 0;
  if (beg + 16 < end) { d0n = adj2(beg + 16, li); d1n = adj2(beg + 16, li + 8); }
  u32 d0 = adj2(beg, li), d1 = adj2(beg, li + 8);
  uint4 rv0 = ld16(H, d0 * 128u + fg * 16u);
  uint4 rv1 = ld16(H, d1 * 128u + fg * 16u);
  float sd0 = sd[d0 * 8u + fg], sd1 = sd[d1 * 8u + fg];

  for (int e = beg; e < end; e += 16) {
    u32 d0nn = 0, d1nn = 0;
    if (e + 32 < end) { d0nn = adj2(e + 32, li); d1nn = adj2(e + 32, li + 8); }
    int mc = end - e; if (mc > 16) mc = 16;
    float z0 = sS + sd0, z1 = sS + sd1;
    float w0 = __expf(-(z0 > 0.f ? z0 : 0.2f * z0));
    float w1 = __expf(-(z1 > 0.f ? z1 : 0.2f * z1));
    w0 = li < mc ? w0 : 0.f;
    w1 = (li + 8) < mc ? w1 : 0.f;
    rsum += w0 + w1;
    bool hn = (e + 16) < end;
    uint4 rv0N = {}, rv1N = {};
    float sd0N = 0.f, sd1N = 0.f;
    if (hn) {
      rv0N = ld16(H, d0n * 128u + fg * 16u);
      rv1N = ld16(H, d1n * 128u + fg * 16u);
      sd0N = sd[d0n * 8u + fg];
      sd1N = sd[d1n * 8u + fg];
    }
    f32x2 W0 = {w0, w0}, W1v = {w1, w1};
    acc2[0] += W0 * up2(rv0.x);
    acc2[1] += W0 * up2(rv0.y);
    acc2[2] += W0 * up2(rv0.z);
    acc2[3] += W0 * up2(rv0.w);
    acc2[0] += W1v * up2(rv1.x);
    acc2[1] += W1v * up2(rv1.y);
    acc2[2] += W1v * up2(rv1.z);
    acc2[3] += W1v * up2(rv1.w);
    if (hn) { rv0 = rv0N; rv1 = rv1N; sd0 = sd0N; sd1 = sd1N; }
    d0n = d0nn; d1n = d1nn;
  }
  #pragma unroll
  for (int mask = 8; mask < 64; mask <<= 1) {
    rsum += __shfl_xor(rsum, mask);
    #pragma unroll
    for (int k = 0; k < 4; k++) {
      acc2[k].x += __shfl_xor(acc2[k].x, mask);
      acc2[k].y += __shfl_xor(acc2[k].y, mask);
    }
  }
  if (li == 0) {
    float inv = 1.f / rsum;
    float o[8];
    #pragma unroll
    for (int k = 0; k < 4; k++) {
      o[2 * k]     = elu_fast(acc2[k].x * inv);
      o[2 * k + 1] = elu_fast(acc2[k].y * inv);
    }
    float4* Ov = reinterpret_cast<float4*>(outp);
    Ov[(size_t)node * 16 + fg * 2]     = make_float4(o[0], o[1], o[2], o[3]);
    Ov[(size_t)node * 16 + fg * 2 + 1] = make_float4(o[4], o[5], o[6], o[7]);
  }
}

extern "C" void kernel_launch(void* const* d_in, const int* in_sizes, int n_in,
                              void* d_out, int out_size, void* d_ws, size_t ws_size,
                              hipStream_t stream) {
  const float* x  = (const float*)d_in[0];
  const int*   ei = (const int*)d_in[1];
  const float* W1 = (const float*)d_in[2];
  const float* a1 = (const float*)d_in[3];
  const float* W2 = (const float*)d_in[4];
  const float* a2 = (const float*)d_in[5];
  float* out = (float*)d_out;

  int N = in_sizes[0] / TNFEAT;   // 50000
  int E = in_sizes[1] / 2;        // 850000
  const int* src = ei;
  const int* dst = ei + E;
  int NB = (N + 1023) / 1024;

  char* base = (char*)d_ws;
  size_t off = 0;
  auto take = [&](size_t bytes) { char* p = base + off; off = (off + bytes + 255) & ~(size_t)255; return p; };
  u16*   xb    = (u16*)take((size_t)N * TNFEAT * 2);       // 12.8 MB
  u16*   h2p   = (u16*)take((size_t)N * C2 * 2);           // 6.4 MB
  u16*   w1hi  = (u16*)take(65536 * 2);
  u16*   w1lo  = (u16*)take(65536 * 2);
  u16*   w2hi  = (u16*)take(32768 * 2);
  u16*   w2lo  = (u16*)take(32768 * 2);
  u16*   vhi   = (u16*)take(2048 * 2);
  u16*   vlo   = (u16*)take(2048 * 2);
  float* s1s   = (float*)take((size_t)N * 8 * 4);
  float* s1d   = (float*)take((size_t)N * 8 * 4);
  float* s2s   = (float*)take((size_t)N * 8 * 4);
  float* s2d   = (float*)take((size_t)N * 8 * 4);
  int*   deg   = (int*)take((size_t)N * 4);
  int*   offs  = (int*)take((size_t)(N + 1) * 4);
  int*   cur   = (int*)take((size_t)N * 4);
  int*   loc   = (int*)take((size_t)N * 4);
  int*   bsum  = (int*)take(64 * 4);
  int*   adj   = (int*)take((size_t)E * 4);

  // CSR build (by src)
  hipLaunchKernelGGL(k_zero, dim3((N + 255) / 256), dim3(256), 0, stream, deg, N);
  hipLaunchKernelGGL(k_hist, dim3((E + 255) / 256), dim3(256), 0, stream, src, deg, E);
  hipLaunchKernelGGL(k_bscan1, dim3(NB), dim3(1024), 0, stream, deg, loc, bsum, N);
  hipLaunchKernelGGL(k_bscan2, dim3(1), dim3(64), 0, stream, bsum, NB);
  hipLaunchKernelGGL(k_offs, dim3(NB), dim3(1024), 0, stream, loc, bsum, deg, offs, cur, N);
  hipLaunchKernelGGL(k_fill, dim3((E + 255) / 256), dim3(256), 0, stream, src, dst, cur, adj, E);

  // Weight packing + score-projection vectors (single launch)
  hipLaunchKernelGGL(k_packAll, dim3(392), dim3(256), 0, stream,
                     W1, W2, a1, w1hi, w1lo, w2hi, w2lo, vhi, vlo);

  // Layer 1 prep: xb + layer-1 scores
  hipLaunchKernelGGL(k_xprep, dim3((N + 63) / 64), dim3(256), 0, stream,
                     x, vhi, vlo, xb, s1s, s1d, N);

  // Fused: aggregation + GEMM1-apply + GEMM2 + layer-2 scores
  hipLaunchKernelGGL(k_l12, dim3((N + 15) / 16), dim3(1024), 0, stream,
                     xb, s1s, s1d, offs, adj, w1hi, w1lo, w2hi, w2lo, a2,
                     h2p, s2s, s2d, N);

  // Layer 2 aggregation
  hipLaunchKernelGGL(k_agg2, dim3((N + 3) / 4), dim3(256), 0, stream,
                     h2p, s2s, s2d, offs, adj, out, N);
}